// Round 1
// baseline (744.058 us; speedup 1.0000x reference)
//
#include <hip/hip_runtime.h>
#include <stdint.h>

typedef unsigned short ushort_t;
typedef __attribute__((ext_vector_type(8))) __bf16 bf16x8;
typedef __attribute__((ext_vector_type(4))) float f32x4;

#define HIDDEN 2048
#define NHEADS 16
#define HDIM 128
#define SEQ 2048
#define BATCH 2
#define MROWS (BATCH*SEQ)

__device__ __forceinline__ ushort_t f2bf(float f) {
  uint32_t u = __float_as_uint(f);
  u += 0x7FFFu + ((u >> 16) & 1u);
  return (ushort_t)(u >> 16);
}
__device__ __forceinline__ float bf2f(ushort_t h) {
  return __uint_as_float((uint32_t)h << 16);
}

__device__ __forceinline__ f32x4 mfma16(bf16x8 a, bf16x8 b, f32x4 c) {
  return __builtin_amdgcn_mfma_f32_16x16x32_bf16(a, b, c, 0, 0, 0);
}

// ---------------- fp32 -> bf16 convert ----------------
__global__ void cvt_kernel(const float* __restrict__ in, ushort_t* __restrict__ out, int n4) {
  int i = blockIdx.x * blockDim.x + threadIdx.x;
  if (i < n4) {
    float4 v = ((const float4*)in)[i];
    uint32_t lo = (uint32_t)f2bf(v.x) | ((uint32_t)f2bf(v.y) << 16);
    uint32_t hi = (uint32_t)f2bf(v.z) | ((uint32_t)f2bf(v.w) << 16);
    ((uint2*)out)[i] = make_uint2(lo, hi);
  }
}

// ---------------- shared 128x128x2048 GEMM core (Y = X * W^T) ----------------
// Ag: points at X row m0 (row stride HIDDEN). Bg: points at W row n0 (row stride HIDDEN).
__device__ __forceinline__ void gemm128_core(const ushort_t* __restrict__ Ag,
                                             const ushort_t* __restrict__ Bg,
                                             ushort_t* As, ushort_t* Bs,
                                             f32x4 acc[4][4], int tid) {
  const int lane = tid & 63, wv = tid >> 6;
  const int r4 = lane >> 2, c8 = (lane & 3) << 3;
  const int wm = (wv >> 1) * 64, wn = (wv & 1) * 64;
  const int mq = lane & 15, quad = lane >> 4;

  for (int k0 = 0; k0 < HIDDEN; k0 += 32) {
#pragma unroll
    for (int cc = 0; cc < 2; ++cc) {
      int chunk = wv + cc * 4;
      const ushort_t* ga = Ag + (size_t)(chunk * 16 + r4) * HIDDEN + k0 + c8;
      const ushort_t* gb = Bg + (size_t)(chunk * 16 + r4) * HIDDEN + k0 + c8;
      __builtin_amdgcn_global_load_lds((__attribute__((address_space(1))) void*)ga,
                                       (__attribute__((address_space(3))) void*)(As + chunk * 512),
                                       16, 0, 0);
      __builtin_amdgcn_global_load_lds((__attribute__((address_space(1))) void*)gb,
                                       (__attribute__((address_space(3))) void*)(Bs + chunk * 512),
                                       16, 0, 0);
    }
    __syncthreads();
    bf16x8 a[4], b[4];
#pragma unroll
    for (int i = 0; i < 4; ++i) a[i] = *(const bf16x8*)(As + (wm + i * 16 + mq) * 32 + quad * 8);
#pragma unroll
    for (int j = 0; j < 4; ++j) b[j] = *(const bf16x8*)(Bs + (wn + j * 16 + mq) * 32 + quad * 8);
#pragma unroll
    for (int i = 0; i < 4; ++i)
#pragma unroll
      for (int j = 0; j < 4; ++j)
        acc[i][j] = mfma16(a[i], b[j], acc[i][j]);
    __syncthreads();
  }
}

// ---------------- fused QKV projection ----------------
__global__ __launch_bounds__(256) void qkv_gemm(const ushort_t* __restrict__ X,
                                                const ushort_t* __restrict__ Wq,
                                                const ushort_t* __restrict__ Wk,
                                                const ushort_t* __restrict__ Wv,
                                                ushort_t* __restrict__ Q,
                                                ushort_t* __restrict__ K,
                                                ushort_t* __restrict__ Vt) {
  __shared__ __align__(16) ushort_t As[128 * 32];
  __shared__ __align__(16) ushort_t Bs[128 * 32];
  const int tid = threadIdx.x;
  const int m0 = blockIdx.x * 128;
  const int nglob = blockIdx.y * 128;
  const int which = nglob >> 11;     // 0:Q 1:K 2:V
  const int n0 = nglob & 2047;
  const ushort_t* W = (which == 0) ? Wq : ((which == 1) ? Wk : Wv);

  f32x4 acc[4][4];
  const f32x4 zf = {0.f, 0.f, 0.f, 0.f};
#pragma unroll
  for (int i = 0; i < 4; ++i)
#pragma unroll
    for (int j = 0; j < 4; ++j) acc[i][j] = zf;

  gemm128_core(X + (size_t)m0 * HIDDEN, W + (size_t)n0 * HIDDEN, As, Bs, acc, tid);

  const int lane = tid & 63, wv = tid >> 6;
  const int wm = (wv >> 1) * 64, wn = (wv & 1) * 64;
  const int mq = lane & 15, quad = lane >> 4;
#pragma unroll
  for (int i = 0; i < 4; ++i)
#pragma unroll
    for (int j = 0; j < 4; ++j)
#pragma unroll
      for (int r = 0; r < 4; ++r) {
        int m = m0 + wm + i * 16 + quad * 4 + r;
        int o = n0 + wn + j * 16 + mq;
        int b = m >> 11, s = m & (SEQ - 1);
        int h = o >> 7, d = o & (HDIM - 1);
        ushort_t val = f2bf(acc[i][j][r]);
        if (which == 2)
          Vt[((size_t)(b * NHEADS + h) * HDIM + d) * SEQ + s] = val;
        else {
          ushort_t* dst = (which == 0) ? Q : K;
          dst[((size_t)(b * NHEADS + h) * SEQ + s) * HDIM + d] = val;
        }
      }
}

// ---------------- RoPE over Q and K ----------------
__global__ void rope_kernel(ushort_t* __restrict__ Q, ushort_t* __restrict__ K) {
  int i = blockIdx.x * blockDim.x + threadIdx.x;   // BATCH*NHEADS*SEQ*64 threads
  int d = i & 63;
  int s = (i >> 6) & (SEQ - 1);
  int bh = i >> 17;
  size_t base = ((size_t)bh * SEQ + s) * HDIM;
  // inv_freq = 10000^{-d/64} = 2^{-d * log2(10000)/64}
  float inv = exp2f((float)d * -0.2076205059304601f);
  float ang = (float)s * inv;
  float sn, cs;
  sincosf(ang, &sn, &cs);
  float q0 = bf2f(Q[base + d]), q1 = bf2f(Q[base + d + 64]);
  Q[base + d]      = f2bf(q0 * cs - q1 * sn);
  Q[base + d + 64] = f2bf(q1 * cs + q0 * sn);
  float k0 = bf2f(K[base + d]), k1 = bf2f(K[base + d + 64]);
  K[base + d]      = f2bf(k0 * cs - k1 * sn);
  K[base + d + 64] = f2bf(k1 * cs + k0 * sn);
}

// ---------------- causal flash attention ----------------
// grid: (S/128, BATCH*NHEADS). 4 waves, each owns 32 q-rows.
__global__ __launch_bounds__(256, 2) void flash_kernel(const ushort_t* __restrict__ Q,
                                                       const ushort_t* __restrict__ K,
                                                       const ushort_t* __restrict__ Vt,
                                                       ushort_t* __restrict__ Ao) {
  __shared__ __align__(16) ushort_t sK[128 * 128];  // keys (later: P overlay), XOR-swizzled 16B groups
  __shared__ __align__(16) ushort_t sV[128 * 128];  // V^T tile: rows=d, cols=s, swizzled
  const int tid = threadIdx.x, lane = tid & 63, wv = tid >> 6;
  const int qt = blockIdx.x, bh = blockIdx.y;
  const int mq = lane & 15, quad = lane >> 4;
  const ushort_t* Qb = Q + (size_t)bh * SEQ * HDIM;
  const ushort_t* Kb = K + (size_t)bh * SEQ * HDIM;
  const ushort_t* Vb = Vt + (size_t)bh * HDIM * SEQ;

  // Q fragments (A-layout), rows qt*128 + wv*32 + i*16 + mq
  bf16x8 qf[2][4];
#pragma unroll
  for (int i = 0; i < 2; ++i)
#pragma unroll
    for (int kt = 0; kt < 4; ++kt) {
      int row = qt * 128 + wv * 32 + i * 16 + mq;
      qf[i][kt] = *(const bf16x8*)(Qb + (size_t)row * HDIM + kt * 32 + quad * 8);
    }

  float m_i[2][4], l_i[2][4];
  f32x4 oacc[2][8];
  const f32x4 zf = {0.f, 0.f, 0.f, 0.f};
#pragma unroll
  for (int i = 0; i < 2; ++i)
#pragma unroll
    for (int r = 0; r < 4; ++r) { m_i[i][r] = -1e30f; l_i[i][r] = 0.f; }
#pragma unroll
  for (int i = 0; i < 2; ++i)
#pragma unroll
    for (int n = 0; n < 8; ++n) oacc[i][n] = zf;

  const float scale = 0.08838834764831845f;  // 1/sqrt(128)

  for (int j = 0; j <= qt; ++j) {
    __syncthreads();  // everyone done with previous P / V reads
    // stage K tile (rows=key) and V^T tile (rows=d), 16B per thread per iter
#pragma unroll
    for (int it = 0; it < 8; ++it) {
      int idx = it * 256 + tid;
      int r = idx >> 4, g = idx & 15;
      int gs = g ^ (r & 7);
      *(uint4*)(sK + r * 128 + gs * 8) =
          *(const uint4*)(Kb + (size_t)(j * 128 + r) * HDIM + g * 8);
      *(uint4*)(sV + r * 128 + gs * 8) =
          *(const uint4*)(Vb + (size_t)r * SEQ + j * 128 + g * 8);
    }
    __syncthreads();

    // S = Q K^T  (per wave: 32 rows x 128 keys)
    f32x4 sacc[2][8];
#pragma unroll
    for (int i = 0; i < 2; ++i)
#pragma unroll
      for (int n = 0; n < 8; ++n) sacc[i][n] = zf;
#pragma unroll
    for (int kt = 0; kt < 4; ++kt) {
      bf16x8 kf[8];
#pragma unroll
      for (int n = 0; n < 8; ++n) {
        int row = n * 16 + mq;
        kf[n] = *(const bf16x8*)(sK + row * 128 + (((kt * 4 + quad) ^ (row & 7)) * 8));
      }
#pragma unroll
      for (int i = 0; i < 2; ++i)
#pragma unroll
        for (int n = 0; n < 8; ++n)
          sacc[i][n] = mfma16(qf[i][kt], kf[n], sacc[i][n]);
    }

    // online softmax (fp32)
    const bool diag = (j == qt);
#pragma unroll
    for (int i = 0; i < 2; ++i) {
#pragma unroll
      for (int r = 0; r < 4; ++r) {
        int row = qt * 128 + wv * 32 + i * 16 + quad * 4 + r;
        float rm = -1e30f;
#pragma unroll
        for (int n = 0; n < 8; ++n) {
          float v = sacc[i][n][r] * scale;
          if (diag && (j * 128 + n * 16 + mq) > row) v = -1e30f;
          sacc[i][n][r] = v;
          rm = fmaxf(rm, v);
        }
        for (int off = 1; off < 16; off <<= 1) rm = fmaxf(rm, __shfl_xor(rm, off, 64));
        float mnew = fmaxf(m_i[i][r], rm);
        float alpha = __expf(m_i[i][r] - mnew);
        m_i[i][r] = mnew;
        float rs = 0.f;
#pragma unroll
        for (int n = 0; n < 8; ++n) {
          float p = __expf(sacc[i][n][r] - mnew);
          sacc[i][n][r] = p;
          rs += p;
        }
        for (int off = 1; off < 16; off <<= 1) rs += __shfl_xor(rs, off, 64);
        l_i[i][r] = l_i[i][r] * alpha + rs;
#pragma unroll
        for (int n = 0; n < 8; ++n) oacc[i][n][r] *= alpha;
      }
    }

    __syncthreads();  // all waves done reading K before P overlay
    // write P (bf16) into sK overlay, same swizzle; each wave owns rows wv*32..wv*32+31
#pragma unroll
    for (int i = 0; i < 2; ++i)
#pragma unroll
      for (int n = 0; n < 8; ++n)
#pragma unroll
        for (int r = 0; r < 4; ++r) {
          int row = wv * 32 + i * 16 + quad * 4 + r;
          int col = n * 16 + mq;
          sK[row * 128 + (((col >> 3) ^ (row & 7)) * 8) + (col & 7)] = f2bf(sacc[i][n][r]);
        }

    // O += P V  (k dim = 128 keys)
#pragma unroll
    for (int kt = 0; kt < 4; ++kt) {
      bf16x8 pf[2];
#pragma unroll
      for (int i = 0; i < 2; ++i) {
        int row = wv * 32 + i * 16 + mq;
        pf[i] = *(const bf16x8*)(sK + row * 128 + (((kt * 4 + quad) ^ (row & 7)) * 8));
      }
#pragma unroll
      for (int n = 0; n < 8; ++n) {
        int rowv = n * 16 + mq;
        bf16x8 vf = *(const bf16x8*)(sV + rowv * 128 + (((kt * 4 + quad) ^ (rowv & 7)) * 8));
#pragma unroll
        for (int i = 0; i < 2; ++i)
          oacc[i][n] = mfma16(pf[i], vf, oacc[i][n]);
      }
    }
  }

  // epilogue: O /= l, write to (B,S,NH*HD) bf16
  const int b = bh >> 4, h = bh & 15;
#pragma unroll
  for (int i = 0; i < 2; ++i)
#pragma unroll
    for (int r = 0; r < 4; ++r) {
      float inv = 1.f / l_i[i][r];
      int srow = qt * 128 + wv * 32 + i * 16 + quad * 4 + r;
      size_t obase = ((size_t)(b * SEQ + srow)) * (NHEADS * HDIM) + h * HDIM;
#pragma unroll
      for (int n = 0; n < 8; ++n)
        Ao[obase + n * 16 + mq] = f2bf(oacc[i][n][r] * inv);
    }
}

// ---------------- output projection (fp32 out) ----------------
__global__ __launch_bounds__(256) void out_gemm(const ushort_t* __restrict__ Ain,
                                                const ushort_t* __restrict__ Wo,
                                                float* __restrict__ Y) {
  __shared__ __align__(16) ushort_t As[128 * 32];
  __shared__ __align__(16) ushort_t Bs[128 * 32];
  const int tid = threadIdx.x;
  const int m0 = blockIdx.x * 128;
  const int n0 = blockIdx.y * 128;

  f32x4 acc[4][4];
  const f32x4 zf = {0.f, 0.f, 0.f, 0.f};
#pragma unroll
  for (int i = 0; i < 4; ++i)
#pragma unroll
    for (int j = 0; j < 4; ++j) acc[i][j] = zf;

  gemm128_core(Ain + (size_t)m0 * HIDDEN, Wo + (size_t)n0 * HIDDEN, As, Bs, acc, tid);

  const int lane = tid & 63, wv = tid >> 6;
  const int wm = (wv >> 1) * 64, wn = (wv & 1) * 64;
  const int mq = lane & 15, quad = lane >> 4;
#pragma unroll
  for (int i = 0; i < 4; ++i)
#pragma unroll
    for (int j = 0; j < 4; ++j)
#pragma unroll
      for (int r = 0; r < 4; ++r) {
        int m = m0 + wm + i * 16 + quad * 4 + r;
        int o = n0 + wn + j * 16 + mq;
        Y[(size_t)m * HIDDEN + o] = acc[i][j][r];
      }
}

extern "C" void kernel_launch(void* const* d_in, const int* in_sizes, int n_in,
                              void* d_out, int out_size, void* d_ws, size_t ws_size,
                              hipStream_t stream) {
  const float* hs = (const float*)d_in[0];
  const float* Wq = (const float*)d_in[1];
  const float* Wk = (const float*)d_in[2];
  const float* Wv = (const float*)d_in[3];
  const float* Wo = (const float*)d_in[4];
  float* out = (float*)d_out;

  ushort_t* ws  = (ushort_t*)d_ws;
  ushort_t* Xb  = ws;
  ushort_t* Wqb = Xb  + (size_t)MROWS * HIDDEN;
  ushort_t* Wkb = Wqb + (size_t)HIDDEN * HIDDEN;
  ushort_t* Wvb = Wkb + (size_t)HIDDEN * HIDDEN;
  ushort_t* Wob = Wvb + (size_t)HIDDEN * HIDDEN;
  ushort_t* Qb  = Wob + (size_t)HIDDEN * HIDDEN;
  ushort_t* Kb  = Qb  + (size_t)MROWS * HIDDEN;
  ushort_t* Vtb = Kb  + (size_t)MROWS * HIDDEN;
  ushort_t* Ao  = Vtb + (size_t)MROWS * HIDDEN;

  cvt_kernel<<<(MROWS * HIDDEN / 4) / 256, 256, 0, stream>>>(hs, Xb, MROWS * HIDDEN / 4);
  cvt_kernel<<<(HIDDEN * HIDDEN / 4) / 256, 256, 0, stream>>>(Wq, Wqb, HIDDEN * HIDDEN / 4);
  cvt_kernel<<<(HIDDEN * HIDDEN / 4) / 256, 256, 0, stream>>>(Wk, Wkb, HIDDEN * HIDDEN / 4);
  cvt_kernel<<<(HIDDEN * HIDDEN / 4) / 256, 256, 0, stream>>>(Wv, Wvb, HIDDEN * HIDDEN / 4);
  cvt_kernel<<<(HIDDEN * HIDDEN / 4) / 256, 256, 0, stream>>>(Wo, Wob, HIDDEN * HIDDEN / 4);

  qkv_gemm<<<dim3(MROWS / 128, 3 * HIDDEN / 128), 256, 0, stream>>>(Xb, Wqb, Wkb, Wvb, Qb, Kb, Vtb);
  rope_kernel<<<(BATCH * NHEADS * SEQ * 64) / 256, 256, 0, stream>>>(Qb, Kb);
  flash_kernel<<<dim3(SEQ / 128, BATCH * NHEADS), 256, 0, stream>>>(Qb, Kb, Vtb, Ao);
  out_gemm<<<dim3(MROWS / 128, HIDDEN / 128), 256, 0, stream>>>(Ao, Wob, out);
}

// Round 2
// 644.984 us; speedup vs baseline: 1.1536x; 1.1536x over previous
//
#include <hip/hip_runtime.h>
#include <stdint.h>

typedef unsigned short ushort_t;
typedef __attribute__((ext_vector_type(8))) __bf16 bf16x8;
typedef __attribute__((ext_vector_type(4))) float f32x4;

#define HIDDEN 2048
#define NHEADS 16
#define HDIM 128
#define SEQ 2048
#define BATCH 2
#define MROWS (BATCH*SEQ)

#define AS1 __attribute__((address_space(1)))
#define AS3 __attribute__((address_space(3)))

__device__ __forceinline__ ushort_t f2bf(float f) {
  uint32_t u = __float_as_uint(f);
  u += 0x7FFFu + ((u >> 16) & 1u);
  return (ushort_t)(u >> 16);
}
__device__ __forceinline__ float bf2f(ushort_t h) {
  return __uint_as_float((uint32_t)h << 16);
}

__device__ __forceinline__ f32x4 mfma16(bf16x8 a, bf16x8 b, f32x4 c) {
  return __builtin_amdgcn_mfma_f32_16x16x32_bf16(a, b, c, 0, 0, 0);
}

// ---------------- fp32 -> bf16 convert ----------------
__global__ void cvt_kernel(const float* __restrict__ in, ushort_t* __restrict__ out, int n4) {
  int i = blockIdx.x * blockDim.x + threadIdx.x;
  if (i < n4) {
    float4 v = ((const float4*)in)[i];
    uint32_t lo = (uint32_t)f2bf(v.x) | ((uint32_t)f2bf(v.y) << 16);
    uint32_t hi = (uint32_t)f2bf(v.z) | ((uint32_t)f2bf(v.w) << 16);
    ((uint2*)out)[i] = make_uint2(lo, hi);
  }
}

// ---------------- shared 128x128x2048 GEMM core (Y = X * W^T) ----------------
__device__ __forceinline__ void gemm128_core(const ushort_t* __restrict__ Ag,
                                             const ushort_t* __restrict__ Bg,
                                             ushort_t* As, ushort_t* Bs,
                                             f32x4 acc[4][4], int tid) {
  const int lane = tid & 63, wv = tid >> 6;
  const int r4 = lane >> 2, c8 = (lane & 3) << 3;
  const int wm = (wv >> 1) * 64, wn = (wv & 1) * 64;
  const int mq = lane & 15, quad = lane >> 4;

  for (int k0 = 0; k0 < HIDDEN; k0 += 32) {
#pragma unroll
    for (int cc = 0; cc < 2; ++cc) {
      int chunk = wv + cc * 4;
      const ushort_t* ga = Ag + (size_t)(chunk * 16 + r4) * HIDDEN + k0 + c8;
      const ushort_t* gb = Bg + (size_t)(chunk * 16 + r4) * HIDDEN + k0 + c8;
      __builtin_amdgcn_global_load_lds((AS1 void*)ga, (AS3 void*)(As + chunk * 512), 16, 0, 0);
      __builtin_amdgcn_global_load_lds((AS1 void*)gb, (AS3 void*)(Bs + chunk * 512), 16, 0, 0);
    }
    __syncthreads();
    bf16x8 a[4], b[4];
#pragma unroll
    for (int i = 0; i < 4; ++i) a[i] = *(const bf16x8*)(As + (wm + i * 16 + mq) * 32 + quad * 8);
#pragma unroll
    for (int j = 0; j < 4; ++j) b[j] = *(const bf16x8*)(Bs + (wn + j * 16 + mq) * 32 + quad * 8);
#pragma unroll
    for (int i = 0; i < 4; ++i)
#pragma unroll
      for (int j = 0; j < 4; ++j)
        acc[i][j] = mfma16(a[i], b[j], acc[i][j]);
    __syncthreads();
  }
}

// ---------------- fused QKV projection (1D grid, XCD-swizzled) ----------------
__global__ __launch_bounds__(256) void qkv_gemm(const ushort_t* __restrict__ X,
                                                const ushort_t* __restrict__ Wq,
                                                const ushort_t* __restrict__ Wk,
                                                const ushort_t* __restrict__ Wv,
                                                ushort_t* __restrict__ Q,
                                                ushort_t* __restrict__ K,
                                                ushort_t* __restrict__ Vt) {
  __shared__ __align__(16) ushort_t As[128 * 32];
  __shared__ __align__(16) ushort_t Bs[128 * 32];
  const int tid = threadIdx.x;
  // XCD swizzle: pin each weight n-tile to one XCD's L2
  const int lin = blockIdx.x;
  const int xcd = lin & 7, s = lin >> 3;
  const int by = xcd + 8 * (s % 6);      // 0..47
  const int bx = s / 6;                  // 0..31
  const int m0 = bx * 128;
  const int nglob = by * 128;
  const int which = nglob >> 11;     // 0:Q 1:K 2:V
  const int n0 = nglob & 2047;
  const ushort_t* W = (which == 0) ? Wq : ((which == 1) ? Wk : Wv);

  f32x4 acc[4][4];
  const f32x4 zf = {0.f, 0.f, 0.f, 0.f};
#pragma unroll
  for (int i = 0; i < 4; ++i)
#pragma unroll
    for (int j = 0; j < 4; ++j) acc[i][j] = zf;

  gemm128_core(X + (size_t)m0 * HIDDEN, W + (size_t)n0 * HIDDEN, As, Bs, acc, tid);

  const int lane = tid & 63, wv = tid >> 6;
  const int wm = (wv >> 1) * 64, wn = (wv & 1) * 64;
  const int mq = lane & 15, quad = lane >> 4;
#pragma unroll
  for (int i = 0; i < 4; ++i)
#pragma unroll
    for (int j = 0; j < 4; ++j)
#pragma unroll
      for (int r = 0; r < 4; ++r) {
        int m = m0 + wm + i * 16 + quad * 4 + r;
        int o = n0 + wn + j * 16 + mq;
        int b = m >> 11, sq = m & (SEQ - 1);
        int h = o >> 7, d = o & (HDIM - 1);
        ushort_t val = f2bf(acc[i][j][r]);
        if (which == 2)
          Vt[((size_t)(b * NHEADS + h) * HDIM + d) * SEQ + sq] = val;
        else {
          ushort_t* dst = (which == 0) ? Q : K;
          dst[((size_t)(b * NHEADS + h) * SEQ + sq) * HDIM + d] = val;
        }
      }
}

// ---------------- RoPE over Q and K (scale 1/sqrt(d) folded into Q) ----------------
__global__ void rope_kernel(ushort_t* __restrict__ Q, ushort_t* __restrict__ K) {
  int i = blockIdx.x * blockDim.x + threadIdx.x;
  int d = i & 63;
  int s = (i >> 6) & (SEQ - 1);
  int bh = i >> 17;
  size_t base = ((size_t)bh * SEQ + s) * HDIM;
  float inv = exp2f((float)d * -0.2076205059304601f);
  float ang = (float)s * inv;
  float sn, cs;
  sincosf(ang, &sn, &cs);
  const float scale = 0.08838834764831845f;  // 1/sqrt(128), folded into Q
  float q0 = bf2f(Q[base + d]), q1 = bf2f(Q[base + d + 64]);
  Q[base + d]      = f2bf((q0 * cs - q1 * sn) * scale);
  Q[base + d + 64] = f2bf((q1 * cs + q0 * sn) * scale);
  float k0 = bf2f(K[base + d]), k1 = bf2f(K[base + d + 64]);
  K[base + d]      = f2bf(k0 * cs - k1 * sn);
  K[base + d + 64] = f2bf(k1 * cs + k0 * sn);
}

// ---------------- causal flash attention (XCD-swizzled, async staging) ----------------
// 1D grid of 512 blocks. xcd = id&7 ; bh pinned to XCD so K/V stay in that L2.
__global__ __launch_bounds__(256, 2) void flash_kernel(const ushort_t* __restrict__ Q,
                                                       const ushort_t* __restrict__ K,
                                                       const ushort_t* __restrict__ Vt,
                                                       ushort_t* __restrict__ Ao) {
  __shared__ __align__(16) ushort_t sK[128 * 128];  // keys / P overlay, XOR-swizzled 16B groups
  __shared__ __align__(16) ushort_t sV[128 * 128];  // V^T tile rows=d cols=s, swizzled
  const int tid = threadIdx.x, lane = tid & 63, wv = tid >> 6;
  const int lin = blockIdx.x;
  const int xcd = lin & 7, slot = lin >> 3;
  const int bh = xcd * 4 + (slot & 3);   // 4 bh per XCD
  const int qt = slot >> 2;              // 0..15
  const int mq = lane & 15, quad = lane >> 4;
  const int rr = lane >> 4, g = lane & 15;  // staging: sub-row / 16B group
  const ushort_t* Qb = Q + (size_t)bh * SEQ * HDIM;
  const ushort_t* Kb = K + (size_t)bh * SEQ * HDIM;
  const ushort_t* Vb = Vt + (size_t)bh * HDIM * SEQ;

  // Q fragments (A-layout), rows qt*128 + wv*32 + i*16 + mq  (pre-scaled by rope)
  bf16x8 qf[2][4];
#pragma unroll
  for (int i = 0; i < 2; ++i)
#pragma unroll
    for (int kt = 0; kt < 4; ++kt) {
      int row = qt * 128 + wv * 32 + i * 16 + mq;
      qf[i][kt] = *(const bf16x8*)(Qb + (size_t)row * HDIM + kt * 32 + quad * 8);
    }

  float m_i[2][4], l_i[2][4];
  f32x4 oacc[2][8];
  const f32x4 zf = {0.f, 0.f, 0.f, 0.f};
#pragma unroll
  for (int i = 0; i < 2; ++i)
#pragma unroll
    for (int r = 0; r < 4; ++r) { m_i[i][r] = -1e30f; l_i[i][r] = 0.f; }
#pragma unroll
  for (int i = 0; i < 2; ++i)
#pragma unroll
    for (int n = 0; n < 8; ++n) oacc[i][n] = zf;

  for (int j = 0; j <= qt; ++j) {
    __syncthreads();  // previous P / V reads complete
    // async DMA staging: per wave 8 chunks of K + 8 of V; each chunk = 4 rows x 256B.
    // XOR swizzle achieved by permuting SOURCE column group (involutive).
#pragma unroll
    for (int t = 0; t < 8; ++t) {
      int chunk = wv * 8 + t;
      int row = chunk * 4 + rr;
      int gs = (g ^ (row & 7)) * 8;
      __builtin_amdgcn_global_load_lds((AS1 void*)(Kb + (size_t)(j * 128 + row) * HDIM + gs),
                                       (AS3 void*)(sK + chunk * 512), 16, 0, 0);
      __builtin_amdgcn_global_load_lds((AS1 void*)(Vb + (size_t)row * SEQ + j * 128 + gs),
                                       (AS3 void*)(sV + chunk * 512), 16, 0, 0);
    }
    __syncthreads();

    // S = Q K^T  (per wave: 32 rows x 128 keys); Q pre-scaled
    f32x4 sacc[2][8];
#pragma unroll
    for (int i = 0; i < 2; ++i)
#pragma unroll
      for (int n = 0; n < 8; ++n) sacc[i][n] = zf;
#pragma unroll
    for (int kt = 0; kt < 4; ++kt) {
      bf16x8 kf[8];
#pragma unroll
      for (int n = 0; n < 8; ++n) {
        int row = n * 16 + mq;
        kf[n] = *(const bf16x8*)(sK + row * 128 + (((kt * 4 + quad) ^ (row & 7)) * 8));
      }
#pragma unroll
      for (int i = 0; i < 2; ++i)
#pragma unroll
        for (int n = 0; n < 8; ++n)
          sacc[i][n] = mfma16(qf[i][kt], kf[n], sacc[i][n]);
    }

    // online softmax (fp32)
    const bool diag = (j == qt);
#pragma unroll
    for (int i = 0; i < 2; ++i) {
#pragma unroll
      for (int r = 0; r < 4; ++r) {
        int row = qt * 128 + wv * 32 + i * 16 + quad * 4 + r;
        float rm = -1e30f;
#pragma unroll
        for (int n = 0; n < 8; ++n) {
          float v = sacc[i][n][r];
          if (diag && (j * 128 + n * 16 + mq) > row) v = -1e30f;
          sacc[i][n][r] = v;
          rm = fmaxf(rm, v);
        }
        for (int off = 1; off < 16; off <<= 1) rm = fmaxf(rm, __shfl_xor(rm, off, 64));
        float mnew = fmaxf(m_i[i][r], rm);
        float alpha = __expf(m_i[i][r] - mnew);
        m_i[i][r] = mnew;
        float rs = 0.f;
#pragma unroll
        for (int n = 0; n < 8; ++n) {
          float p = __expf(sacc[i][n][r] - mnew);
          sacc[i][n][r] = p;
          rs += p;
        }
        for (int off = 1; off < 16; off <<= 1) rs += __shfl_xor(rs, off, 64);
        l_i[i][r] = l_i[i][r] * alpha + rs;
#pragma unroll
        for (int n = 0; n < 8; ++n) oacc[i][n][r] *= alpha;
      }
    }

    __syncthreads();  // all waves done reading K before P overlay
#pragma unroll
    for (int i = 0; i < 2; ++i)
#pragma unroll
      for (int n = 0; n < 8; ++n)
#pragma unroll
        for (int r = 0; r < 4; ++r) {
          int row = wv * 32 + i * 16 + quad * 4 + r;
          int col = n * 16 + mq;
          sK[row * 128 + (((col >> 3) ^ (row & 7)) * 8) + (col & 7)] = f2bf(sacc[i][n][r]);
        }

    // O += P V
#pragma unroll
    for (int kt = 0; kt < 4; ++kt) {
      bf16x8 pf[2];
#pragma unroll
      for (int i = 0; i < 2; ++i) {
        int row = wv * 32 + i * 16 + mq;
        pf[i] = *(const bf16x8*)(sK + row * 128 + (((kt * 4 + quad) ^ (row & 7)) * 8));
      }
#pragma unroll
      for (int n = 0; n < 8; ++n) {
        int rowv = n * 16 + mq;
        bf16x8 vf = *(const bf16x8*)(sV + rowv * 128 + (((kt * 4 + quad) ^ (rowv & 7)) * 8));
#pragma unroll
        for (int i = 0; i < 2; ++i)
          oacc[i][n] = mfma16(pf[i], vf, oacc[i][n]);
      }
    }
  }

  // epilogue: O /= l, write to (B,S,NH*HD) bf16
  const int b = bh >> 4, h = bh & 15;
#pragma unroll
  for (int i = 0; i < 2; ++i)
#pragma unroll
    for (int r = 0; r < 4; ++r) {
      float inv = 1.f / l_i[i][r];
      int srow = qt * 128 + wv * 32 + i * 16 + quad * 4 + r;
      size_t obase = ((size_t)(b * SEQ + srow)) * (NHEADS * HDIM) + h * HDIM;
#pragma unroll
      for (int n = 0; n < 8; ++n)
        Ao[obase + n * 16 + mq] = f2bf(oacc[i][n][r] * inv);
    }
}

// ---------------- output projection (fp32 out, XCD-swizzled) ----------------
__global__ __launch_bounds__(256) void out_gemm(const ushort_t* __restrict__ Ain,
                                                const ushort_t* __restrict__ Wo,
                                                float* __restrict__ Y) {
  __shared__ __align__(16) ushort_t As[128 * 32];
  __shared__ __align__(16) ushort_t Bs[128 * 32];
  const int tid = threadIdx.x;
  const int lin = blockIdx.x;
  const int xcd = lin & 7, s = lin >> 3;
  const int by = xcd + 8 * (s & 1);   // 0..15
  const int bx = s >> 1;              // 0..31
  const int m0 = bx * 128;
  const int n0 = by * 128;

  f32x4 acc[4][4];
  const f32x4 zf = {0.f, 0.f, 0.f, 0.f};
#pragma unroll
  for (int i = 0; i < 4; ++i)
#pragma unroll
    for (int j = 0; j < 4; ++j) acc[i][j] = zf;

  gemm128_core(Ain + (size_t)m0 * HIDDEN, Wo + (size_t)n0 * HIDDEN, As, Bs, acc, tid);

  const int lane = tid & 63, wv = tid >> 6;
  const int wm = (wv >> 1) * 64, wn = (wv & 1) * 64;
  const int mq = lane & 15, quad = lane >> 4;
#pragma unroll
  for (int i = 0; i < 4; ++i)
#pragma unroll
    for (int j = 0; j < 4; ++j)
#pragma unroll
      for (int r = 0; r < 4; ++r) {
        int m = m0 + wm + i * 16 + quad * 4 + r;
        int o = n0 + wn + j * 16 + mq;
        Y[(size_t)m * HIDDEN + o] = acc[i][j][r];
      }
}

extern "C" void kernel_launch(void* const* d_in, const int* in_sizes, int n_in,
                              void* d_out, int out_size, void* d_ws, size_t ws_size,
                              hipStream_t stream) {
  const float* hs = (const float*)d_in[0];
  const float* Wq = (const float*)d_in[1];
  const float* Wk = (const float*)d_in[2];
  const float* Wv = (const float*)d_in[3];
  const float* Wo = (const float*)d_in[4];
  float* out = (float*)d_out;

  ushort_t* ws  = (ushort_t*)d_ws;
  ushort_t* Xb  = ws;
  ushort_t* Wqb = Xb  + (size_t)MROWS * HIDDEN;
  ushort_t* Wkb = Wqb + (size_t)HIDDEN * HIDDEN;
  ushort_t* Wvb = Wkb + (size_t)HIDDEN * HIDDEN;
  ushort_t* Wob = Wvb + (size_t)HIDDEN * HIDDEN;
  ushort_t* Qb  = Wob + (size_t)HIDDEN * HIDDEN;
  ushort_t* Kb  = Qb  + (size_t)MROWS * HIDDEN;
  ushort_t* Vtb = Kb  + (size_t)MROWS * HIDDEN;
  ushort_t* Ao  = Vtb + (size_t)MROWS * HIDDEN;

  cvt_kernel<<<(MROWS * HIDDEN / 4) / 256, 256, 0, stream>>>(hs, Xb, MROWS * HIDDEN / 4);
  cvt_kernel<<<(HIDDEN * HIDDEN / 4) / 256, 256, 0, stream>>>(Wq, Wqb, HIDDEN * HIDDEN / 4);
  cvt_kernel<<<(HIDDEN * HIDDEN / 4) / 256, 256, 0, stream>>>(Wk, Wkb, HIDDEN * HIDDEN / 4);
  cvt_kernel<<<(HIDDEN * HIDDEN / 4) / 256, 256, 0, stream>>>(Wv, Wvb, HIDDEN * HIDDEN / 4);
  cvt_kernel<<<(HIDDEN * HIDDEN / 4) / 256, 256, 0, stream>>>(Wo, Wob, HIDDEN * HIDDEN / 4);

  qkv_gemm<<<dim3(MROWS / 128 * 48), 256, 0, stream>>>(Xb, Wqb, Wkb, Wvb, Qb, Kb, Vtb);
  rope_kernel<<<(BATCH * NHEADS * SEQ * 64) / 256, 256, 0, stream>>>(Qb, Kb);
  flash_kernel<<<dim3(512), 256, 0, stream>>>(Qb, Kb, Vtb, Ao);
  out_gemm<<<dim3(512), 256, 0, stream>>>(Ao, Wob, out);
}

// Round 3
// 489.806 us; speedup vs baseline: 1.5191x; 1.3168x over previous
//
#include <hip/hip_runtime.h>
#include <stdint.h>

typedef unsigned short ushort_t;
typedef __attribute__((ext_vector_type(8))) __bf16 bf16x8;
typedef __attribute__((ext_vector_type(4))) float f32x4;

#define HIDDEN 2048
#define NHEADS 16
#define HDIM 128
#define SEQ 2048
#define BATCH 2
#define MROWS (BATCH*SEQ)

#define AS1 __attribute__((address_space(1)))
#define AS3 __attribute__((address_space(3)))

__device__ __forceinline__ ushort_t f2bf(float f) {
  uint32_t u = __float_as_uint(f);
  u += 0x7FFFu + ((u >> 16) & 1u);
  return (ushort_t)(u >> 16);
}
__device__ __forceinline__ float bf2f(ushort_t h) {
  return __uint_as_float((uint32_t)h << 16);
}

__device__ __forceinline__ f32x4 mfma16(bf16x8 a, bf16x8 b, f32x4 c) {
  return __builtin_amdgcn_mfma_f32_16x16x32_bf16(a, b, c, 0, 0, 0);
}

// ---------------- fp32 -> bf16 converts ----------------
__global__ void cvt_kernel(const float* __restrict__ in, ushort_t* __restrict__ out, int n4) {
  int i = blockIdx.x * blockDim.x + threadIdx.x;
  if (i < n4) {
    float4 v = ((const float4*)in)[i];
    uint32_t lo = (uint32_t)f2bf(v.x) | ((uint32_t)f2bf(v.y) << 16);
    uint32_t hi = (uint32_t)f2bf(v.z) | ((uint32_t)f2bf(v.w) << 16);
    ((uint2*)out)[i] = make_uint2(lo, hi);
  }
}

// all 4 weights in one launch: blockIdx.y picks the matrix
__global__ void cvt4_kernel(const float* __restrict__ w0, const float* __restrict__ w1,
                            const float* __restrict__ w2, const float* __restrict__ w3,
                            ushort_t* __restrict__ o0, ushort_t* __restrict__ o1,
                            ushort_t* __restrict__ o2, ushort_t* __restrict__ o3) {
  int y = blockIdx.y;
  const float* in = (y == 0) ? w0 : (y == 1) ? w1 : (y == 2) ? w2 : w3;
  ushort_t* out = (y == 0) ? o0 : (y == 1) ? o1 : (y == 2) ? o2 : o3;
  int i = blockIdx.x * blockDim.x + threadIdx.x;
  float4 v = ((const float4*)in)[i];
  uint32_t lo = (uint32_t)f2bf(v.x) | ((uint32_t)f2bf(v.y) << 16);
  uint32_t hi = (uint32_t)f2bf(v.z) | ((uint32_t)f2bf(v.w) << 16);
  ((uint2*)out)[i] = make_uint2(lo, hi);
}

// ---------------- shared 128x128x2048 GEMM core (Y = X * W^T) ----------------
__device__ __forceinline__ void gemm128_core(const ushort_t* __restrict__ Ag,
                                             const ushort_t* __restrict__ Bg,
                                             ushort_t* As, ushort_t* Bs,
                                             f32x4 acc[4][4], int tid) {
  const int lane = tid & 63, wv = tid >> 6;
  const int r4 = lane >> 2, c8 = (lane & 3) << 3;
  const int wm = (wv >> 1) * 64, wn = (wv & 1) * 64;
  const int mq = lane & 15, quad = lane >> 4;

  for (int k0 = 0; k0 < HIDDEN; k0 += 32) {
#pragma unroll
    for (int cc = 0; cc < 2; ++cc) {
      int chunk = wv + cc * 4;
      const ushort_t* ga = Ag + (size_t)(chunk * 16 + r4) * HIDDEN + k0 + c8;
      const ushort_t* gb = Bg + (size_t)(chunk * 16 + r4) * HIDDEN + k0 + c8;
      __builtin_amdgcn_global_load_lds((AS1 void*)ga, (AS3 void*)(As + chunk * 512), 16, 0, 0);
      __builtin_amdgcn_global_load_lds((AS1 void*)gb, (AS3 void*)(Bs + chunk * 512), 16, 0, 0);
    }
    __syncthreads();
    bf16x8 a[4], b[4];
#pragma unroll
    for (int i = 0; i < 4; ++i) a[i] = *(const bf16x8*)(As + (wm + i * 16 + mq) * 32 + quad * 8);
#pragma unroll
    for (int j = 0; j < 4; ++j) b[j] = *(const bf16x8*)(Bs + (wn + j * 16 + mq) * 32 + quad * 8);
#pragma unroll
    for (int i = 0; i < 4; ++i)
#pragma unroll
      for (int j = 0; j < 4; ++j)
        acc[i][j] = mfma16(a[i], b[j], acc[i][j]);
    __syncthreads();
  }
}

// ---------------- fused QKV projection (1D grid, XCD-swizzled) ----------------
__global__ __launch_bounds__(256) void qkv_gemm(const ushort_t* __restrict__ X,
                                                const ushort_t* __restrict__ Wq,
                                                const ushort_t* __restrict__ Wk,
                                                const ushort_t* __restrict__ Wv,
                                                ushort_t* __restrict__ Q,
                                                ushort_t* __restrict__ K,
                                                ushort_t* __restrict__ Vt) {
  __shared__ __align__(16) ushort_t smem[2][128 * 32];
  ushort_t* As = smem[0];
  ushort_t* Bs = smem[1];
  ushort_t* trans = &smem[0][0];   // 8192 ushorts = 64 x 128 bf16 tile
  const int tid = threadIdx.x;
  const int lin = blockIdx.x;
  const int xcd = lin & 7, s = lin >> 3;
  const int by = xcd + 8 * (s % 6);      // 0..47
  const int bx = s / 6;                  // 0..31
  const int m0 = bx * 128;
  const int nglob = by * 128;
  const int which = nglob >> 11;     // 0:Q 1:K 2:V
  const int n0 = nglob & 2047;
  const ushort_t* W = (which == 0) ? Wq : ((which == 1) ? Wk : Wv);

  f32x4 acc[4][4];
  const f32x4 zf = {0.f, 0.f, 0.f, 0.f};
#pragma unroll
  for (int i = 0; i < 4; ++i)
#pragma unroll
    for (int j = 0; j < 4; ++j) acc[i][j] = zf;

  gemm128_core(X + (size_t)m0 * HIDDEN, W + (size_t)n0 * HIDDEN, As, Bs, acc, tid);

  const int lane = tid & 63, wv = tid >> 6;
  const int wm = (wv >> 1) * 64, wn = (wv & 1) * 64;
  const int mq = lane & 15, quad = lane >> 4;
  const int b = m0 >> 11, s0 = m0 & (SEQ - 1);
  const int h = n0 >> 7;

  if (which != 2) {
    ushort_t* dst = (which == 0) ? Q : K;
#pragma unroll
    for (int i = 0; i < 4; ++i)
#pragma unroll
      for (int j = 0; j < 4; ++j)
#pragma unroll
        for (int r = 0; r < 4; ++r) {
          int m = m0 + wm + i * 16 + quad * 4 + r;
          int o = n0 + wn + j * 16 + mq;
          int bb = m >> 11, sq = m & (SEQ - 1);
          int hh = o >> 7, d = o & (HDIM - 1);
          dst[((size_t)(bb * NHEADS + hh) * SEQ + sq) * HDIM + d] = f2bf(acc[i][j][r]);
        }
  } else {
    // V: transpose through LDS -> coalesced stores to Vt (B,NH,HD,SEQ)
#pragma unroll
    for (int p = 0; p < 2; ++p) {
      __syncthreads();
      if ((wv & 1) == p) {
#pragma unroll
        for (int i = 0; i < 4; ++i)
#pragma unroll
          for (int j = 0; j < 4; ++j)
#pragma unroll
            for (int r = 0; r < 4; ++r) {
              int m = wm + i * 16 + quad * 4 + r;     // 0..127 (seq within tile)
              int oo = j * 16 + mq;                   // 0..63  (d within half)
              int mg = m >> 3;
              trans[oo * 128 + ((mg ^ (oo & 7)) * 8) + (m & 7)] = f2bf(acc[i][j][r]);
            }
      }
      __syncthreads();
#pragma unroll
      for (int it = 0; it < 4; ++it) {
        int oo = it * 16 + (tid >> 4);
        int g = tid & 15;
        uint4 v = *(const uint4*)(trans + oo * 128 + ((g ^ (oo & 7)) * 8));
        *(uint4*)(Vt + (((size_t)(b * NHEADS + h) * HDIM + (p * 64 + oo)) * SEQ + s0 + g * 8)) = v;
      }
    }
  }
}

// ---------------- RoPE over Q and K (1/sqrt(d) folded into Q) ----------------
__global__ void rope_kernel(ushort_t* __restrict__ Q, ushort_t* __restrict__ K) {
  int i = blockIdx.x * blockDim.x + threadIdx.x;
  int d = i & 63;
  int s = (i >> 6) & (SEQ - 1);
  int bh = i >> 17;
  size_t base = ((size_t)bh * SEQ + s) * HDIM;
  float inv = exp2f((float)d * -0.2076205059304601f);
  float ang = (float)s * inv;
  float sn, cs;
  sincosf(ang, &sn, &cs);
  const float scale = 0.08838834764831845f;  // 1/sqrt(128)
  float q0 = bf2f(Q[base + d]), q1 = bf2f(Q[base + d + 64]);
  Q[base + d]      = f2bf((q0 * cs - q1 * sn) * scale);
  Q[base + d + 64] = f2bf((q1 * cs + q0 * sn) * scale);
  float k0 = bf2f(K[base + d]), k1 = bf2f(K[base + d + 64]);
  K[base + d]      = f2bf(k0 * cs - k1 * sn);
  K[base + d + 64] = f2bf(k1 * cs + k0 * sn);
}

// ---------------- causal flash attention ----------------
// 64-key KV steps, double-buffered K, prefetch overlapped with QK^T+softmax.
// LDS: sK 2x16KB + sV 16KB + sP 16KB = 64KB -> 2 blocks/CU.
__global__ __launch_bounds__(256, 2) void flash_kernel(const ushort_t* __restrict__ Q,
                                                       const ushort_t* __restrict__ K,
                                                       const ushort_t* __restrict__ Vt,
                                                       ushort_t* __restrict__ Ao) {
  __shared__ __align__(16) ushort_t sK[2][64 * 128];
  __shared__ __align__(16) ushort_t sV[128 * 64];   // V^T: rows=d, cols=key
  __shared__ __align__(16) ushort_t sP[128 * 64];   // P: rows=q, cols=key (per-wave bands)
  const int tid = threadIdx.x, lane = tid & 63, wv = tid >> 6;
  const int lin = blockIdx.x;
  const int xcd = lin & 7, slot = lin >> 3;
  const int bh = xcd * 4 + (slot & 3);
  const int qt = slot >> 2;              // 0..15
  const int mq = lane & 15, quad = lane >> 4;
  const ushort_t* Qb = Q + (size_t)bh * SEQ * HDIM;
  const ushort_t* Kb = K + (size_t)bh * SEQ * HDIM;
  const ushort_t* Vb = Vt + (size_t)bh * HDIM * SEQ;

  // K tile: 64 rows x 128 dims, 16 chunks of 1KB, this wave stages 4
  auto stageK = [&](int j, ushort_t* dst) {
    int rr = lane >> 4, g = lane & 15;
#pragma unroll
    for (int t = 0; t < 4; ++t) {
      int chunk = wv * 4 + t;
      int row = chunk * 4 + rr;
      int gs = (g ^ (row & 7)) * 8;
      __builtin_amdgcn_global_load_lds((AS1 void*)(Kb + (size_t)(j * 64 + row) * HDIM + gs),
                                       (AS3 void*)(dst + chunk * 512), 16, 0, 0);
    }
  };
  // V^T tile: 128 rows(d) x 64 cols(key)
  auto stageV = [&](int j) {
    int rr = lane >> 3, g = lane & 7;
#pragma unroll
    for (int t = 0; t < 4; ++t) {
      int chunk = wv * 4 + t;
      int row = chunk * 8 + rr;
      int gs = (g ^ (row & 7)) * 8;
      __builtin_amdgcn_global_load_lds((AS1 void*)(Vb + (size_t)row * SEQ + j * 64 + gs),
                                       (AS3 void*)(sV + chunk * 512), 16, 0, 0);
    }
  };

  // Q fragments (A-layout), rows qt*128 + wv*32 + i*16 + mq (pre-scaled by rope)
  bf16x8 qf[2][4];
#pragma unroll
  for (int i = 0; i < 2; ++i)
#pragma unroll
    for (int kt = 0; kt < 4; ++kt) {
      int row = qt * 128 + wv * 32 + i * 16 + mq;
      qf[i][kt] = *(const bf16x8*)(Qb + (size_t)row * HDIM + kt * 32 + quad * 8);
    }

  float m_i[2][4], l_i[2][4];
  f32x4 oacc[2][8];
  const f32x4 zf = {0.f, 0.f, 0.f, 0.f};
#pragma unroll
  for (int i = 0; i < 2; ++i)
#pragma unroll
    for (int r = 0; r < 4; ++r) { m_i[i][r] = -1e30f; l_i[i][r] = 0.f; }
#pragma unroll
  for (int i = 0; i < 2; ++i)
#pragma unroll
    for (int n = 0; n < 8; ++n) oacc[i][n] = zf;

  const int jmax = 2 * qt + 1;
  stageK(0, sK[0]);

  for (int j = 0; j <= jmax; ++j) {
    const int p = j & 1;
    __syncthreads();   // B1: K(j) drained; sV free (PV of j-1 done by all waves)
    stageV(j);
    if (j < jmax) stageK(j + 1, sK[p ^ 1]);

    // S = Q K^T  (per wave: 32 q-rows x 64 keys)
    const ushort_t* sKp = sK[p];
    f32x4 sacc[2][4];
#pragma unroll
    for (int i = 0; i < 2; ++i)
#pragma unroll
      for (int n = 0; n < 4; ++n) sacc[i][n] = zf;
#pragma unroll
    for (int kt = 0; kt < 4; ++kt) {
      bf16x8 kf[4];
#pragma unroll
      for (int n = 0; n < 4; ++n) {
        int row = n * 16 + mq;
        kf[n] = *(const bf16x8*)(sKp + row * 128 + (((kt * 4 + quad) ^ (row & 7)) * 8));
      }
#pragma unroll
      for (int i = 0; i < 2; ++i)
#pragma unroll
        for (int n = 0; n < 4; ++n)
          sacc[i][n] = mfma16(qf[i][kt], kf[n], sacc[i][n]);
    }

    // online softmax (fp32)
    const bool diag = (j >= 2 * qt);
#pragma unroll
    for (int i = 0; i < 2; ++i) {
#pragma unroll
      for (int r = 0; r < 4; ++r) {
        int row = qt * 128 + wv * 32 + i * 16 + quad * 4 + r;
        float rm = -1e30f;
#pragma unroll
        for (int n = 0; n < 4; ++n) {
          float v = sacc[i][n][r];
          if (diag && (j * 64 + n * 16 + mq) > row) v = -1e30f;
          sacc[i][n][r] = v;
          rm = fmaxf(rm, v);
        }
        for (int off = 1; off < 16; off <<= 1) rm = fmaxf(rm, __shfl_xor(rm, off, 64));
        float mnew = fmaxf(m_i[i][r], rm);
        float alpha = __expf(m_i[i][r] - mnew);
        m_i[i][r] = mnew;
        float rs = 0.f;
#pragma unroll
        for (int n = 0; n < 4; ++n) {
          float pv = __expf(sacc[i][n][r] - mnew);
          sacc[i][n][r] = pv;
          rs += pv;
        }
        for (int off = 1; off < 16; off <<= 1) rs += __shfl_xor(rs, off, 64);
        l_i[i][r] = l_i[i][r] * alpha + rs;
#pragma unroll
        for (int n = 0; n < 8; ++n) oacc[i][n][r] *= alpha;
      }
    }

    // write P to own rows of sP (no cross-wave hazard)
#pragma unroll
    for (int i = 0; i < 2; ++i)
#pragma unroll
      for (int n = 0; n < 4; ++n)
#pragma unroll
        for (int r = 0; r < 4; ++r) {
          int row = wv * 32 + i * 16 + quad * 4 + r;
          int c = n * 16 + mq;
          sP[row * 64 + (((c >> 3) ^ (row & 7)) * 8) + (c & 7)] = f2bf(sacc[i][n][r]);
        }

    __syncthreads();   // B2: V(j) landed (all waves' chunks); K(j+1) mostly landed

    // O += P V   (k dim = 64 keys)
#pragma unroll
    for (int kt = 0; kt < 2; ++kt) {
      bf16x8 pf[2];
#pragma unroll
      for (int i = 0; i < 2; ++i) {
        int row = wv * 32 + i * 16 + mq;
        pf[i] = *(const bf16x8*)(sP + row * 64 + (((kt * 4 + quad) ^ (row & 7)) * 8));
      }
#pragma unroll
      for (int n = 0; n < 8; ++n) {
        int vrow = n * 16 + mq;
        bf16x8 vf = *(const bf16x8*)(sV + vrow * 64 + (((kt * 4 + quad) ^ (vrow & 7)) * 8));
#pragma unroll
        for (int i = 0; i < 2; ++i)
          oacc[i][n] = mfma16(pf[i], vf, oacc[i][n]);
      }
    }
  }

  // epilogue: O /= l, coalesced store via sP round-trip (2 passes of 64 d-cols)
  const int b = bh >> 4, h = bh & 15;
#pragma unroll
  for (int p = 0; p < 2; ++p) {
    __syncthreads();
#pragma unroll
    for (int i = 0; i < 2; ++i)
#pragma unroll
      for (int nn = 0; nn < 4; ++nn) {
        int n = p * 4 + nn;
#pragma unroll
        for (int r = 0; r < 4; ++r) {
          int row = wv * 32 + i * 16 + quad * 4 + r;
          int c = nn * 16 + mq;
          float inv = 1.f / l_i[i][r];
          sP[row * 64 + (((c >> 3) ^ (row & 7)) * 8) + (c & 7)] = f2bf(oacc[i][n][r] * inv);
        }
      }
    __syncthreads();
#pragma unroll
    for (int it = 0; it < 4; ++it) {
      int row = it * 32 + (tid >> 3);
      int g = tid & 7;
      uint4 v = *(const uint4*)(sP + row * 64 + ((g ^ (row & 7)) * 8));
      *(uint4*)(Ao + ((size_t)(b * SEQ + qt * 128 + row)) * (NHEADS * HDIM) + h * HDIM + p * 64 + g * 8) = v;
    }
  }
}

// ---------------- output projection (fp32 out, XCD-swizzled) ----------------
__global__ __launch_bounds__(256) void out_gemm(const ushort_t* __restrict__ Ain,
                                                const ushort_t* __restrict__ Wo,
                                                float* __restrict__ Y) {
  __shared__ __align__(16) ushort_t smem[2][128 * 32];
  ushort_t* As = smem[0];
  ushort_t* Bs = smem[1];
  const int tid = threadIdx.x;
  const int lin = blockIdx.x;
  const int xcd = lin & 7, s = lin >> 3;
  const int by = xcd + 8 * (s & 1);   // 0..15
  const int bx = s >> 1;              // 0..31
  const int m0 = bx * 128;
  const int n0 = by * 128;

  f32x4 acc[4][4];
  const f32x4 zf = {0.f, 0.f, 0.f, 0.f};
#pragma unroll
  for (int i = 0; i < 4; ++i)
#pragma unroll
    for (int j = 0; j < 4; ++j) acc[i][j] = zf;

  gemm128_core(Ain + (size_t)m0 * HIDDEN, Wo + (size_t)n0 * HIDDEN, As, Bs, acc, tid);

  const int lane = tid & 63, wv = tid >> 6;
  const int wm = (wv >> 1) * 64, wn = (wv & 1) * 64;
  const int mq = lane & 15, quad = lane >> 4;
#pragma unroll
  for (int i = 0; i < 4; ++i)
#pragma unroll
    for (int j = 0; j < 4; ++j)
#pragma unroll
      for (int r = 0; r < 4; ++r) {
        int m = m0 + wm + i * 16 + quad * 4 + r;
        int o = n0 + wn + j * 16 + mq;
        Y[(size_t)m * HIDDEN + o] = acc[i][j][r];
      }
}

extern "C" void kernel_launch(void* const* d_in, const int* in_sizes, int n_in,
                              void* d_out, int out_size, void* d_ws, size_t ws_size,
                              hipStream_t stream) {
  const float* hs = (const float*)d_in[0];
  const float* Wq = (const float*)d_in[1];
  const float* Wk = (const float*)d_in[2];
  const float* Wv = (const float*)d_in[3];
  const float* Wo = (const float*)d_in[4];
  float* out = (float*)d_out;

  ushort_t* ws  = (ushort_t*)d_ws;
  ushort_t* Xb  = ws;
  ushort_t* Wqb = Xb  + (size_t)MROWS * HIDDEN;
  ushort_t* Wkb = Wqb + (size_t)HIDDEN * HIDDEN;
  ushort_t* Wvb = Wkb + (size_t)HIDDEN * HIDDEN;
  ushort_t* Wob = Wvb + (size_t)HIDDEN * HIDDEN;
  ushort_t* Qb  = Wob + (size_t)HIDDEN * HIDDEN;
  ushort_t* Kb  = Qb  + (size_t)MROWS * HIDDEN;
  ushort_t* Vtb = Kb  + (size_t)MROWS * HIDDEN;
  ushort_t* Ao  = Vtb + (size_t)MROWS * HIDDEN;

  cvt_kernel<<<(MROWS * HIDDEN / 4) / 256, 256, 0, stream>>>(hs, Xb, MROWS * HIDDEN / 4);
  cvt4_kernel<<<dim3((HIDDEN * HIDDEN / 4) / 256, 4), 256, 0, stream>>>(
      Wq, Wk, Wv, Wo, Wqb, Wkb, Wvb, Wob);

  qkv_gemm<<<dim3(MROWS / 128 * 48), 256, 0, stream>>>(Xb, Wqb, Wkb, Wvb, Qb, Kb, Vtb);
  rope_kernel<<<(BATCH * NHEADS * SEQ * 64) / 256, 256, 0, stream>>>(Qb, Kb);
  flash_kernel<<<dim3(512), 256, 0, stream>>>(Qb, Kb, Vtb, Ao);
  out_gemm<<<dim3(512), 256, 0, stream>>>(Ao, Wob, out);
}

// Round 4
// 434.704 us; speedup vs baseline: 1.7116x; 1.1268x over previous
//
#include <hip/hip_runtime.h>
#include <stdint.h>

typedef unsigned short ushort_t;
typedef __attribute__((ext_vector_type(8))) __bf16 bf16x8;
typedef __attribute__((ext_vector_type(4))) float f32x4;

#define HIDDEN 2048
#define NHEADS 16
#define HDIM 128
#define SEQ 2048
#define BATCH 2
#define MROWS (BATCH*SEQ)

#define AS1 __attribute__((address_space(1)))
#define AS3 __attribute__((address_space(3)))

__device__ __forceinline__ ushort_t f2bf(float f) {
  uint32_t u = __float_as_uint(f);
  u += 0x7FFFu + ((u >> 16) & 1u);
  return (ushort_t)(u >> 16);
}
__device__ __forceinline__ float bf2f(ushort_t h) {
  return __uint_as_float((uint32_t)h << 16);
}

__device__ __forceinline__ f32x4 mfma16(bf16x8 a, bf16x8 b, f32x4 c) {
  return __builtin_amdgcn_mfma_f32_16x16x32_bf16(a, b, c, 0, 0, 0);
}

// ---------------- fp32 -> bf16 converts ----------------
__global__ void cvt_kernel(const float* __restrict__ in, ushort_t* __restrict__ out, int n4) {
  int i = blockIdx.x * blockDim.x + threadIdx.x;
  if (i < n4) {
    float4 v = ((const float4*)in)[i];
    uint32_t lo = (uint32_t)f2bf(v.x) | ((uint32_t)f2bf(v.y) << 16);
    uint32_t hi = (uint32_t)f2bf(v.z) | ((uint32_t)f2bf(v.w) << 16);
    ((uint2*)out)[i] = make_uint2(lo, hi);
  }
}

__global__ void cvt4_kernel(const float* __restrict__ w0, const float* __restrict__ w1,
                            const float* __restrict__ w2, const float* __restrict__ w3,
                            ushort_t* __restrict__ o0, ushort_t* __restrict__ o1,
                            ushort_t* __restrict__ o2, ushort_t* __restrict__ o3) {
  int y = blockIdx.y;
  const float* in = (y == 0) ? w0 : (y == 1) ? w1 : (y == 2) ? w2 : w3;
  ushort_t* out = (y == 0) ? o0 : (y == 1) ? o1 : (y == 2) ? o2 : o3;
  int i = blockIdx.x * blockDim.x + threadIdx.x;
  float4 v = ((const float4*)in)[i];
  uint32_t lo = (uint32_t)f2bf(v.x) | ((uint32_t)f2bf(v.y) << 16);
  uint32_t hi = (uint32_t)f2bf(v.z) | ((uint32_t)f2bf(v.w) << 16);
  ((uint2*)out)[i] = make_uint2(lo, hi);
}

// ---------------- shared 128x128x2048 GEMM core (Y = X * W^T) ----------------
__device__ __forceinline__ void gemm128_core(const ushort_t* __restrict__ Ag,
                                             const ushort_t* __restrict__ Bg,
                                             ushort_t* As, ushort_t* Bs,
                                             f32x4 acc[4][4], int tid) {
  const int lane = tid & 63, wv = tid >> 6;
  const int r4 = lane >> 2, c8 = (lane & 3) << 3;
  const int wm = (wv >> 1) * 64, wn = (wv & 1) * 64;
  const int mq = lane & 15, quad = lane >> 4;

  for (int k0 = 0; k0 < HIDDEN; k0 += 32) {
#pragma unroll
    for (int cc = 0; cc < 2; ++cc) {
      int chunk = wv + cc * 4;
      const ushort_t* ga = Ag + (size_t)(chunk * 16 + r4) * HIDDEN + k0 + c8;
      const ushort_t* gb = Bg + (size_t)(chunk * 16 + r4) * HIDDEN + k0 + c8;
      __builtin_amdgcn_global_load_lds((AS1 void*)ga, (AS3 void*)(As + chunk * 512), 16, 0, 0);
      __builtin_amdgcn_global_load_lds((AS1 void*)gb, (AS3 void*)(Bs + chunk * 512), 16, 0, 0);
    }
    __syncthreads();
    bf16x8 a[4], b[4];
#pragma unroll
    for (int i = 0; i < 4; ++i) a[i] = *(const bf16x8*)(As + (wm + i * 16 + mq) * 32 + quad * 8);
#pragma unroll
    for (int j = 0; j < 4; ++j) b[j] = *(const bf16x8*)(Bs + (wn + j * 16 + mq) * 32 + quad * 8);
#pragma unroll
    for (int i = 0; i < 4; ++i)
#pragma unroll
      for (int j = 0; j < 4; ++j)
        acc[i][j] = mfma16(a[i], b[j], acc[i][j]);
    __syncthreads();
  }
}

// ---------------- fused QKV projection (1D grid, XCD-swizzled) ----------------
__global__ __launch_bounds__(256) void qkv_gemm(const ushort_t* __restrict__ X,
                                                const ushort_t* __restrict__ Wq,
                                                const ushort_t* __restrict__ Wk,
                                                const ushort_t* __restrict__ Wv,
                                                ushort_t* __restrict__ Q,
                                                ushort_t* __restrict__ K,
                                                ushort_t* __restrict__ Vt) {
  __shared__ __align__(16) ushort_t smem[2][128 * 32];
  ushort_t* As = smem[0];
  ushort_t* Bs = smem[1];
  ushort_t* trans = &smem[0][0];
  const int tid = threadIdx.x;
  const int lin = blockIdx.x;
  const int xcd = lin & 7, s = lin >> 3;
  const int by = xcd + 8 * (s % 6);
  const int bx = s / 6;
  const int m0 = bx * 128;
  const int nglob = by * 128;
  const int which = nglob >> 11;
  const int n0 = nglob & 2047;
  const ushort_t* W = (which == 0) ? Wq : ((which == 1) ? Wk : Wv);

  f32x4 acc[4][4];
  const f32x4 zf = {0.f, 0.f, 0.f, 0.f};
#pragma unroll
  for (int i = 0; i < 4; ++i)
#pragma unroll
    for (int j = 0; j < 4; ++j) acc[i][j] = zf;

  gemm128_core(X + (size_t)m0 * HIDDEN, W + (size_t)n0 * HIDDEN, As, Bs, acc, tid);

  const int lane = tid & 63, wv = tid >> 6;
  const int wm = (wv >> 1) * 64, wn = (wv & 1) * 64;
  const int mq = lane & 15, quad = lane >> 4;
  const int b = m0 >> 11, s0 = m0 & (SEQ - 1);
  const int h = n0 >> 7;

  if (which != 2) {
    ushort_t* dst = (which == 0) ? Q : K;
#pragma unroll
    for (int i = 0; i < 4; ++i)
#pragma unroll
      for (int j = 0; j < 4; ++j)
#pragma unroll
        for (int r = 0; r < 4; ++r) {
          int m = m0 + wm + i * 16 + quad * 4 + r;
          int o = n0 + wn + j * 16 + mq;
          int bb = m >> 11, sq = m & (SEQ - 1);
          int hh = o >> 7, d = o & (HDIM - 1);
          dst[((size_t)(bb * NHEADS + hh) * SEQ + sq) * HDIM + d] = f2bf(acc[i][j][r]);
        }
  } else {
#pragma unroll
    for (int p = 0; p < 2; ++p) {
      __syncthreads();
      if ((wv & 1) == p) {
#pragma unroll
        for (int i = 0; i < 4; ++i)
#pragma unroll
          for (int j = 0; j < 4; ++j)
#pragma unroll
            for (int r = 0; r < 4; ++r) {
              int m = wm + i * 16 + quad * 4 + r;
              int oo = j * 16 + mq;
              int mg = m >> 3;
              trans[oo * 128 + ((mg ^ (oo & 7)) * 8) + (m & 7)] = f2bf(acc[i][j][r]);
            }
      }
      __syncthreads();
#pragma unroll
      for (int it = 0; it < 4; ++it) {
        int oo = it * 16 + (tid >> 4);
        int g = tid & 15;
        uint4 v = *(const uint4*)(trans + oo * 128 + ((g ^ (oo & 7)) * 8));
        *(uint4*)(Vt + (((size_t)(b * NHEADS + h) * HDIM + (p * 64 + oo)) * SEQ + s0 + g * 8)) = v;
      }
    }
  }
}

// ---------------- RoPE over Q and K (1/sqrt(d) folded into Q) ----------------
__global__ void rope_kernel(ushort_t* __restrict__ Q, ushort_t* __restrict__ K) {
  int i = blockIdx.x * blockDim.x + threadIdx.x;
  int d = i & 63;
  int s = (i >> 6) & (SEQ - 1);
  int bh = i >> 17;
  size_t base = ((size_t)bh * SEQ + s) * HDIM;
  float inv = exp2f((float)d * -0.2076205059304601f);
  float ang = (float)s * inv;
  float sn, cs;
  sincosf(ang, &sn, &cs);
  const float scale = 0.08838834764831845f;
  float q0 = bf2f(Q[base + d]), q1 = bf2f(Q[base + d + 64]);
  Q[base + d]      = f2bf((q0 * cs - q1 * sn) * scale);
  Q[base + d + 64] = f2bf((q1 * cs + q0 * sn) * scale);
  float k0 = bf2f(K[base + d]), k1 = bf2f(K[base + d + 64]);
  K[base + d]      = f2bf(k0 * cs - k1 * sn);
  K[base + d + 64] = f2bf(k1 * cs + k0 * sn);
}

// ---------------- causal flash attention: balanced pairs + transposed scores ----
// 256 blocks (1/CU). Block handles q-tiles T=pair and T=15-pair -> 34 steps of
// 64 keys always. S^T = K*Q^T so softmax rows are per-lane; P^T is wave-private.
// One barrier per step; K/V double-buffered DMA prefetch overlaps whole step.
__global__ __launch_bounds__(256, 1) void flash_kernel(const ushort_t* __restrict__ Q,
                                                       const ushort_t* __restrict__ K,
                                                       const ushort_t* __restrict__ Vt,
                                                       ushort_t* __restrict__ Ao) {
  __shared__ __align__(16) ushort_t sK[2][64 * 128];   // keys: 64 rows x 128 d
  __shared__ __align__(16) ushort_t sV[2][128 * 64];   // V^T: 128 d x 64 keys
  __shared__ __align__(16) ushort_t sP[128 * 64];      // P^T as [q][key], wave-private bands
  ushort_t* sO = &sK[0][0];                            // 128x128 epilogue scratch (32KB)

  const int tid = threadIdx.x, lane = tid & 63, wv = tid >> 6;
  const int lq = lane & 15, quad = lane >> 4;
  const int lin = blockIdx.x;
  const int xcd = lin & 7, slot = lin >> 3;
  const int bh = xcd * 4 + (slot & 3);
  const int pair = slot >> 2;                          // 0..7
  const ushort_t* Qb = Q + (size_t)bh * SEQ * HDIM;
  const ushort_t* Kb = K + (size_t)bh * SEQ * HDIM;
  const ushort_t* Vb = Vt + (size_t)bh * HDIM * SEQ;
  const int b = bh >> 4, h = bh & 15;

  auto stageK = [&](int j, ushort_t* dst) {
    int rr = lane >> 4, g = lane & 15;
#pragma unroll
    for (int t = 0; t < 4; ++t) {
      int chunk = wv * 4 + t;
      int row = chunk * 4 + rr;
      int gs = (g ^ (row & 7)) * 8;
      __builtin_amdgcn_global_load_lds((AS1 void*)(Kb + (size_t)(j * 64 + row) * HDIM + gs),
                                       (AS3 void*)(dst + chunk * 512), 16, 0, 0);
    }
  };
  auto stageV = [&](int j, ushort_t* dst) {
    int rr = lane >> 3, g = lane & 7;
#pragma unroll
    for (int t = 0; t < 4; ++t) {
      int chunk = wv * 4 + t;
      int row = chunk * 8 + rr;
      int gs = (g ^ (row & 7)) * 8;
      __builtin_amdgcn_global_load_lds((AS1 void*)(Vb + (size_t)row * SEQ + j * 64 + gs),
                                       (AS3 void*)(dst + chunk * 512), 16, 0, 0);
    }
  };

  const f32x4 zf = {0.f, 0.f, 0.f, 0.f};

#pragma unroll 1
  for (int phase = 0; phase < 2; ++phase) {
    const int T = phase ? (15 - pair) : pair;
    const int nsteps = 2 * T + 2;

    // Q B-fragments: B[k=d][n=q], q = T*128 + wv*32 + n*16 + lq (rope pre-scaled)
    bf16x8 qf[2][4];
#pragma unroll
    for (int n = 0; n < 2; ++n)
#pragma unroll
      for (int kt = 0; kt < 4; ++kt)
        qf[n][kt] = *(const bf16x8*)(Qb + (size_t)(T * 128 + wv * 32 + n * 16 + lq) * HDIM +
                                     kt * 32 + quad * 8);

    float m_i[2] = {-1e30f, -1e30f}, l_i[2] = {0.f, 0.f};
    f32x4 oacc[8][2];
#pragma unroll
    for (int m = 0; m < 8; ++m)
#pragma unroll
      for (int n = 0; n < 2; ++n) oacc[m][n] = zf;

    __syncthreads();                 // epilogue scratch (sK) free before restaging
    stageK(0, sK[0]);
    stageV(0, sV[0]);
    __syncthreads();                 // drain K(0), V(0)

#pragma unroll 1
    for (int j = 0; j < nsteps; ++j) {
      const int cur = j & 1;
      if (j + 1 < nsteps) {          // prefetch next tiles; drained by end-of-step barrier
        stageK(j + 1, sK[cur ^ 1]);
        stageV(j + 1, sV[cur ^ 1]);
      }

      // S^T = K Q^T : rows=key (m), cols=q (n)
      const ushort_t* sKc = sK[cur];
      f32x4 sacc[4][2];
#pragma unroll
      for (int m = 0; m < 4; ++m)
#pragma unroll
        for (int n = 0; n < 2; ++n) sacc[m][n] = zf;
#pragma unroll
      for (int kt = 0; kt < 4; ++kt) {
        bf16x8 kf[4];
#pragma unroll
        for (int m = 0; m < 4; ++m) {
          int row = m * 16 + lq;
          kf[m] = *(const bf16x8*)(sKc + row * 128 + (((kt * 4 + quad) ^ (row & 7)) * 8));
        }
#pragma unroll
        for (int m = 0; m < 4; ++m)
#pragma unroll
          for (int n = 0; n < 2; ++n)
            sacc[m][n] = mfma16(kf[m], qf[n][kt], sacc[m][n]);
      }

      // per-lane online softmax (each lane owns 16 key-values of one q-row per n)
      const bool diag = (j >= 2 * T);
#pragma unroll
      for (int n = 0; n < 2; ++n) {
        const int qr = wv * 32 + n * 16 + lq;        // tile-local q row (0..127)
        if (diag) {
          const int rowg = T * 128 + qr;
#pragma unroll
          for (int m = 0; m < 4; ++m)
#pragma unroll
            for (int r = 0; r < 4; ++r) {
              int key = j * 64 + m * 16 + quad * 4 + r;
              if (key > rowg) sacc[m][n][r] = -1e30f;
            }
        }
        float rm = -1e30f;
#pragma unroll
        for (int m = 0; m < 4; ++m)
#pragma unroll
          for (int r = 0; r < 4; ++r) rm = fmaxf(rm, sacc[m][n][r]);
        rm = fmaxf(rm, __shfl_xor(rm, 16, 64));
        rm = fmaxf(rm, __shfl_xor(rm, 32, 64));
        float mnew = fmaxf(m_i[n], rm);
        float alpha = __expf(m_i[n] - mnew);
        m_i[n] = mnew;
        float rs = 0.f;
#pragma unroll
        for (int m = 0; m < 4; ++m)
#pragma unroll
          for (int r = 0; r < 4; ++r) {
            float p = __expf(sacc[m][n][r] - mnew);
            sacc[m][n][r] = p;
            rs += p;
          }
        rs += __shfl_xor(rs, 16, 64);
        rs += __shfl_xor(rs, 32, 64);
        l_i[n] = l_i[n] * alpha + rs;
#pragma unroll
        for (int m = 0; m < 8; ++m)
#pragma unroll
          for (int r = 0; r < 4; ++r) oacc[m][n][r] *= alpha;
        // write P^T rows (wave-private; no barrier needed before PV)
#pragma unroll
        for (int m = 0; m < 4; ++m) {
          uint32_t lo = (uint32_t)f2bf(sacc[m][n][0]) | ((uint32_t)f2bf(sacc[m][n][1]) << 16);
          uint32_t hi = (uint32_t)f2bf(sacc[m][n][2]) | ((uint32_t)f2bf(sacc[m][n][3]) << 16);
          int gw = m * 2 + (quad >> 1);
          *(uint2*)(sP + qr * 64 + ((gw ^ (qr & 7)) * 8) + (quad & 1) * 4) = make_uint2(lo, hi);
        }
      }

      // O^T += V^T P^T : rows=d (m), cols=q (n)
      const ushort_t* sVc = sV[cur];
#pragma unroll
      for (int kt = 0; kt < 2; ++kt) {
        bf16x8 pf[2];
#pragma unroll
        for (int n = 0; n < 2; ++n) {
          int qr = wv * 32 + n * 16 + lq;
          pf[n] = *(const bf16x8*)(sP + qr * 64 + (((kt * 4 + quad) ^ (qr & 7)) * 8));
        }
#pragma unroll
        for (int m = 0; m < 8; ++m) {
          int d = m * 16 + lq;
          bf16x8 vf = *(const bf16x8*)(sVc + d * 64 + (((kt * 4 + quad) ^ (d & 7)) * 8));
#pragma unroll
          for (int n = 0; n < 2; ++n)
            oacc[m][n] = mfma16(vf, pf[n], oacc[m][n]);
        }
      }

      __syncthreads();   // single barrier: drains prefetch DMA + guards buffer reuse
    }

    // epilogue: O^T/l -> transpose via LDS -> coalesced bf16 stores
    float inv0 = 1.f / l_i[0], inv1 = 1.f / l_i[1];
#pragma unroll
    for (int n = 0; n < 2; ++n) {
      float inv = n ? inv1 : inv0;
      int qr = wv * 32 + n * 16 + lq;
#pragma unroll
      for (int m = 0; m < 8; ++m) {
        uint32_t lo = (uint32_t)f2bf(oacc[m][n][0] * inv) | ((uint32_t)f2bf(oacc[m][n][1] * inv) << 16);
        uint32_t hi = (uint32_t)f2bf(oacc[m][n][2] * inv) | ((uint32_t)f2bf(oacc[m][n][3] * inv) << 16);
        int gw = m * 2 + (quad >> 1);
        *(uint2*)(sO + qr * 128 + ((gw ^ (qr & 7)) * 8) + (quad & 1) * 4) = make_uint2(lo, hi);
      }
    }
    __syncthreads();
#pragma unroll
    for (int it = 0; it < 8; ++it) {
      int qr = it * 16 + (tid >> 4);
      int g = tid & 15;
      uint4 v = *(const uint4*)(sO + qr * 128 + ((g ^ (qr & 7)) * 8));
      *(uint4*)(Ao + ((size_t)(b * SEQ + T * 128 + qr)) * (NHEADS * HDIM) + h * HDIM + g * 8) = v;
    }
  }
}

// ---------------- output projection (fp32 out, XCD-swizzled) ----------------
__global__ __launch_bounds__(256) void out_gemm(const ushort_t* __restrict__ Ain,
                                                const ushort_t* __restrict__ Wo,
                                                float* __restrict__ Y) {
  __shared__ __align__(16) ushort_t smem[2][128 * 32];
  ushort_t* As = smem[0];
  ushort_t* Bs = smem[1];
  const int tid = threadIdx.x;
  const int lin = blockIdx.x;
  const int xcd = lin & 7, s = lin >> 3;
  const int by = xcd + 8 * (s & 1);
  const int bx = s >> 1;
  const int m0 = bx * 128;
  const int n0 = by * 128;

  f32x4 acc[4][4];
  const f32x4 zf = {0.f, 0.f, 0.f, 0.f};
#pragma unroll
  for (int i = 0; i < 4; ++i)
#pragma unroll
    for (int j = 0; j < 4; ++j) acc[i][j] = zf;

  gemm128_core(Ain + (size_t)m0 * HIDDEN, Wo + (size_t)n0 * HIDDEN, As, Bs, acc, tid);

  const int lane = tid & 63, wv = tid >> 6;
  const int wm = (wv >> 1) * 64, wn = (wv & 1) * 64;
  const int mq = lane & 15, quad = lane >> 4;
#pragma unroll
  for (int i = 0; i < 4; ++i)
#pragma unroll
    for (int j = 0; j < 4; ++j)
#pragma unroll
      for (int r = 0; r < 4; ++r) {
        int m = m0 + wm + i * 16 + quad * 4 + r;
        int o = n0 + wn + j * 16 + mq;
        Y[(size_t)m * HIDDEN + o] = acc[i][j][r];
      }
}

extern "C" void kernel_launch(void* const* d_in, const int* in_sizes, int n_in,
                              void* d_out, int out_size, void* d_ws, size_t ws_size,
                              hipStream_t stream) {
  const float* hs = (const float*)d_in[0];
  const float* Wq = (const float*)d_in[1];
  const float* Wk = (const float*)d_in[2];
  const float* Wv = (const float*)d_in[3];
  const float* Wo = (const float*)d_in[4];
  float* out = (float*)d_out;

  ushort_t* ws  = (ushort_t*)d_ws;
  ushort_t* Xb  = ws;
  ushort_t* Wqb = Xb  + (size_t)MROWS * HIDDEN;
  ushort_t* Wkb = Wqb + (size_t)HIDDEN * HIDDEN;
  ushort_t* Wvb = Wkb + (size_t)HIDDEN * HIDDEN;
  ushort_t* Wob = Wvb + (size_t)HIDDEN * HIDDEN;
  ushort_t* Qb  = Wob + (size_t)HIDDEN * HIDDEN;
  ushort_t* Kb  = Qb  + (size_t)MROWS * HIDDEN;
  ushort_t* Vtb = Kb  + (size_t)MROWS * HIDDEN;
  ushort_t* Ao  = Vtb + (size_t)MROWS * HIDDEN;

  cvt_kernel<<<(MROWS * HIDDEN / 4) / 256, 256, 0, stream>>>(hs, Xb, MROWS * HIDDEN / 4);
  cvt4_kernel<<<dim3((HIDDEN * HIDDEN / 4) / 256, 4), 256, 0, stream>>>(
      Wq, Wk, Wv, Wo, Wqb, Wkb, Wvb, Wob);

  qkv_gemm<<<dim3(MROWS / 128 * 48), 256, 0, stream>>>(Xb, Wqb, Wkb, Wvb, Qb, Kb, Vtb);
  rope_kernel<<<(BATCH * NHEADS * SEQ * 64) / 256, 256, 0, stream>>>(Qb, Kb);
  flash_kernel<<<dim3(256), 256, 0, stream>>>(Qb, Kb, Vtb, Ao);
  out_gemm<<<dim3(512), 256, 0, stream>>>(Ao, Wob, out);
}

// Round 5
// 426.187 us; speedup vs baseline: 1.7458x; 1.0200x over previous
//
#include <hip/hip_runtime.h>
#include <stdint.h>

typedef unsigned short ushort_t;
typedef __attribute__((ext_vector_type(8))) __bf16 bf16x8;
typedef __attribute__((ext_vector_type(4))) float f32x4;

#define HIDDEN 2048
#define NHEADS 16
#define HDIM 128
#define SEQ 2048
#define BATCH 2
#define MROWS (BATCH*SEQ)

#define AS1 __attribute__((address_space(1)))
#define AS3 __attribute__((address_space(3)))

__device__ __forceinline__ ushort_t f2bf(float f) {
  uint32_t u = __float_as_uint(f);
  u += 0x7FFFu + ((u >> 16) & 1u);
  return (ushort_t)(u >> 16);
}
__device__ __forceinline__ float bf2f(ushort_t h) {
  return __uint_as_float((uint32_t)h << 16);
}

__device__ __forceinline__ f32x4 mfma16(bf16x8 a, bf16x8 b, f32x4 c) {
  return __builtin_amdgcn_mfma_f32_16x16x32_bf16(a, b, c, 0, 0, 0);
}

// ---------------- fp32 -> bf16 converts ----------------
__global__ void cvt_kernel(const float* __restrict__ in, ushort_t* __restrict__ out, int n4) {
  int i = blockIdx.x * blockDim.x + threadIdx.x;
  if (i < n4) {
    float4 v = ((const float4*)in)[i];
    uint32_t lo = (uint32_t)f2bf(v.x) | ((uint32_t)f2bf(v.y) << 16);
    uint32_t hi = (uint32_t)f2bf(v.z) | ((uint32_t)f2bf(v.w) << 16);
    ((uint2*)out)[i] = make_uint2(lo, hi);
  }
}

__global__ void cvt4_kernel(const float* __restrict__ w0, const float* __restrict__ w1,
                            const float* __restrict__ w2, const float* __restrict__ w3,
                            ushort_t* __restrict__ o0, ushort_t* __restrict__ o1,
                            ushort_t* __restrict__ o2, ushort_t* __restrict__ o3) {
  int y = blockIdx.y;
  const float* in = (y == 0) ? w0 : (y == 1) ? w1 : (y == 2) ? w2 : w3;
  ushort_t* out = (y == 0) ? o0 : (y == 1) ? o1 : (y == 2) ? o2 : o3;
  int i = blockIdx.x * blockDim.x + threadIdx.x;
  float4 v = ((const float4*)in)[i];
  uint32_t lo = (uint32_t)f2bf(v.x) | ((uint32_t)f2bf(v.y) << 16);
  uint32_t hi = (uint32_t)f2bf(v.z) | ((uint32_t)f2bf(v.w) << 16);
  ((uint2*)out)[i] = make_uint2(lo, hi);
}

// ------- shared 128x128x2048 GEMM core: double-buffered, swizzled LDS -------
// LDS layout per 128x32 tile: row r, col-group g (8 elems) stored at slot
// g ^ ((r>>1)&3)  -> fragment ds_read_b128 is 2-way-only on banks (free).
// K-loop: prefetch(k+1) -> compute(k) -> single barrier (drains DMA + guards swap).
__device__ __forceinline__ void gemm128_core(const ushort_t* __restrict__ Ag,
                                             const ushort_t* __restrict__ Bg,
                                             ushort_t* As, ushort_t* Bs,  // each 2*4096
                                             f32x4 acc[4][4], int tid) {
  const int lane = tid & 63, wv = tid >> 6;
  const int r4 = lane >> 2;
  const int c8 = (((lane & 3) ^ ((r4 >> 1) & 3)) << 3);  // swizzled source col-group
  const int wm = (wv >> 1) * 64, wn = (wv & 1) * 64;
  const int mq = lane & 15, quad = lane >> 4;
  const int sw = (mq >> 1) & 3;                          // per-lane read swizzle

  auto stage = [&](int k0, int buf) {
#pragma unroll
    for (int cc = 0; cc < 2; ++cc) {
      int chunk = wv + cc * 4;
      const ushort_t* ga = Ag + (size_t)(chunk * 16 + r4) * HIDDEN + k0 + c8;
      const ushort_t* gb = Bg + (size_t)(chunk * 16 + r4) * HIDDEN + k0 + c8;
      __builtin_amdgcn_global_load_lds((AS1 void*)ga, (AS3 void*)(As + buf * 4096 + chunk * 512), 16, 0, 0);
      __builtin_amdgcn_global_load_lds((AS1 void*)gb, (AS3 void*)(Bs + buf * 4096 + chunk * 512), 16, 0, 0);
    }
  };

  stage(0, 0);
  __syncthreads();
#pragma unroll 1
  for (int k0 = 0; k0 < HIDDEN; k0 += 32) {
    const int cur = (k0 >> 5) & 1;
    if (k0 + 32 < HIDDEN) stage(k0 + 32, cur ^ 1);
    const ushort_t* A = As + cur * 4096;
    const ushort_t* B = Bs + cur * 4096;
    bf16x8 a[4], b[4];
#pragma unroll
    for (int i = 0; i < 4; ++i)
      a[i] = *(const bf16x8*)(A + (wm + i * 16 + mq) * 32 + ((quad ^ sw) << 3));
#pragma unroll
    for (int j = 0; j < 4; ++j)
      b[j] = *(const bf16x8*)(B + (wn + j * 16 + mq) * 32 + ((quad ^ sw) << 3));
#pragma unroll
    for (int i = 0; i < 4; ++i)
#pragma unroll
      for (int j = 0; j < 4; ++j)
        acc[i][j] = mfma16(a[i], b[j], acc[i][j]);
    __syncthreads();
  }
}

// ---------------- fused QKV projection (1D grid, XCD-swizzled) ----------------
__global__ __launch_bounds__(256) void qkv_gemm(const ushort_t* __restrict__ X,
                                                const ushort_t* __restrict__ Wq,
                                                const ushort_t* __restrict__ Wk,
                                                const ushort_t* __restrict__ Wv,
                                                ushort_t* __restrict__ Q,
                                                ushort_t* __restrict__ K,
                                                ushort_t* __restrict__ Vt) {
  __shared__ __align__(16) ushort_t As[2][128 * 32];
  __shared__ __align__(16) ushort_t Bs[2][128 * 32];
  ushort_t* trans = &As[0][0];   // 8192 ushorts = 64 x 128 bf16 epilogue scratch
  const int tid = threadIdx.x;
  const int lin = blockIdx.x;
  const int xcd = lin & 7, s = lin >> 3;
  const int by = xcd + 8 * (s % 6);
  const int bx = s / 6;
  const int m0 = bx * 128;
  const int nglob = by * 128;
  const int which = nglob >> 11;
  const int n0 = nglob & 2047;
  const ushort_t* W = (which == 0) ? Wq : ((which == 1) ? Wk : Wv);

  f32x4 acc[4][4];
  const f32x4 zf = {0.f, 0.f, 0.f, 0.f};
#pragma unroll
  for (int i = 0; i < 4; ++i)
#pragma unroll
    for (int j = 0; j < 4; ++j) acc[i][j] = zf;

  gemm128_core(X + (size_t)m0 * HIDDEN, W + (size_t)n0 * HIDDEN, &As[0][0], &Bs[0][0], acc, tid);

  const int lane = tid & 63, wv = tid >> 6;
  const int wm = (wv >> 1) * 64, wn = (wv & 1) * 64;
  const int mq = lane & 15, quad = lane >> 4;
  const int b = m0 >> 11, s0 = m0 & (SEQ - 1);
  const int h = n0 >> 7;

  if (which != 2) {
    ushort_t* dst = (which == 0) ? Q : K;
#pragma unroll
    for (int i = 0; i < 4; ++i)
#pragma unroll
      for (int j = 0; j < 4; ++j)
#pragma unroll
        for (int r = 0; r < 4; ++r) {
          int m = m0 + wm + i * 16 + quad * 4 + r;
          int o = n0 + wn + j * 16 + mq;
          int bb = m >> 11, sq = m & (SEQ - 1);
          int hh = o >> 7, d = o & (HDIM - 1);
          dst[((size_t)(bb * NHEADS + hh) * SEQ + sq) * HDIM + d] = f2bf(acc[i][j][r]);
        }
  } else {
    // V: transpose through LDS -> coalesced stores to Vt (B,NH,HD,SEQ)
#pragma unroll
    for (int p = 0; p < 2; ++p) {
      __syncthreads();
      if ((wv & 1) == p) {
#pragma unroll
        for (int i = 0; i < 4; ++i)
#pragma unroll
          for (int j = 0; j < 4; ++j)
#pragma unroll
            for (int r = 0; r < 4; ++r) {
              int m = wm + i * 16 + quad * 4 + r;
              int oo = j * 16 + mq;
              int mg = m >> 3;
              trans[oo * 128 + ((mg ^ (oo & 7)) * 8) + (m & 7)] = f2bf(acc[i][j][r]);
            }
      }
      __syncthreads();
#pragma unroll
      for (int it = 0; it < 4; ++it) {
        int oo = it * 16 + (tid >> 4);
        int g = tid & 15;
        uint4 v = *(const uint4*)(trans + oo * 128 + ((g ^ (oo & 7)) * 8));
        *(uint4*)(Vt + (((size_t)(b * NHEADS + h) * HDIM + (p * 64 + oo)) * SEQ + s0 + g * 8)) = v;
      }
    }
  }
}

// ---------------- RoPE over Q and K (1/sqrt(d) folded into Q) ----------------
__global__ void rope_kernel(ushort_t* __restrict__ Q, ushort_t* __restrict__ K) {
  int i = blockIdx.x * blockDim.x + threadIdx.x;
  int d = i & 63;
  int s = (i >> 6) & (SEQ - 1);
  int bh = i >> 17;
  size_t base = ((size_t)bh * SEQ + s) * HDIM;
  float inv = exp2f((float)d * -0.2076205059304601f);
  float ang = (float)s * inv;
  float sn, cs;
  sincosf(ang, &sn, &cs);
  const float scale = 0.08838834764831845f;
  float q0 = bf2f(Q[base + d]), q1 = bf2f(Q[base + d + 64]);
  Q[base + d]      = f2bf((q0 * cs - q1 * sn) * scale);
  Q[base + d + 64] = f2bf((q1 * cs + q0 * sn) * scale);
  float k0 = bf2f(K[base + d]), k1 = bf2f(K[base + d + 64]);
  K[base + d]      = f2bf(k0 * cs - k1 * sn);
  K[base + d + 64] = f2bf(k1 * cs + k0 * sn);
}

// ---------------- causal flash attention: balanced pairs + transposed scores ----
__global__ __launch_bounds__(256, 1) void flash_kernel(const ushort_t* __restrict__ Q,
                                                       const ushort_t* __restrict__ K,
                                                       const ushort_t* __restrict__ Vt,
                                                       ushort_t* __restrict__ Ao) {
  __shared__ __align__(16) ushort_t sK[2][64 * 128];   // keys: 64 rows x 128 d
  __shared__ __align__(16) ushort_t sV[2][128 * 64];   // V^T: 128 d x 64 keys
  __shared__ __align__(16) ushort_t sP[128 * 64];      // P^T as [q][key], wave-private bands
  ushort_t* sO = &sK[0][0];                            // 128x128 epilogue scratch (32KB)

  const int tid = threadIdx.x, lane = tid & 63, wv = tid >> 6;
  const int lq = lane & 15, quad = lane >> 4;
  const int lin = blockIdx.x;
  const int xcd = lin & 7, slot = lin >> 3;
  const int bh = xcd * 4 + (slot & 3);
  const int pair = slot >> 2;                          // 0..7
  const ushort_t* Qb = Q + (size_t)bh * SEQ * HDIM;
  const ushort_t* Kb = K + (size_t)bh * SEQ * HDIM;
  const ushort_t* Vb = Vt + (size_t)bh * HDIM * SEQ;
  const int b = bh >> 4, h = bh & 15;

  auto stageK = [&](int j, ushort_t* dst) {
    int rr = lane >> 4, g = lane & 15;
#pragma unroll
    for (int t = 0; t < 4; ++t) {
      int chunk = wv * 4 + t;
      int row = chunk * 4 + rr;
      int gs = (g ^ (row & 7)) * 8;
      __builtin_amdgcn_global_load_lds((AS1 void*)(Kb + (size_t)(j * 64 + row) * HDIM + gs),
                                       (AS3 void*)(dst + chunk * 512), 16, 0, 0);
    }
  };
  auto stageV = [&](int j, ushort_t* dst) {
    int rr = lane >> 3, g = lane & 7;
#pragma unroll
    for (int t = 0; t < 4; ++t) {
      int chunk = wv * 4 + t;
      int row = chunk * 8 + rr;
      int gs = (g ^ (row & 7)) * 8;
      __builtin_amdgcn_global_load_lds((AS1 void*)(Vb + (size_t)row * SEQ + j * 64 + gs),
                                       (AS3 void*)(dst + chunk * 512), 16, 0, 0);
    }
  };

  const f32x4 zf = {0.f, 0.f, 0.f, 0.f};

#pragma unroll 1
  for (int phase = 0; phase < 2; ++phase) {
    const int T = phase ? (15 - pair) : pair;
    const int nsteps = 2 * T + 2;

    bf16x8 qf[2][4];
#pragma unroll
    for (int n = 0; n < 2; ++n)
#pragma unroll
      for (int kt = 0; kt < 4; ++kt)
        qf[n][kt] = *(const bf16x8*)(Qb + (size_t)(T * 128 + wv * 32 + n * 16 + lq) * HDIM +
                                     kt * 32 + quad * 8);

    float m_i[2] = {-1e30f, -1e30f}, l_i[2] = {0.f, 0.f};
    f32x4 oacc[8][2];
#pragma unroll
    for (int m = 0; m < 8; ++m)
#pragma unroll
      for (int n = 0; n < 2; ++n) oacc[m][n] = zf;

    __syncthreads();
    stageK(0, sK[0]);
    stageV(0, sV[0]);
    __syncthreads();

#pragma unroll 1
    for (int j = 0; j < nsteps; ++j) {
      const int cur = j & 1;
      if (j + 1 < nsteps) {
        stageK(j + 1, sK[cur ^ 1]);
        stageV(j + 1, sV[cur ^ 1]);
      }

      const ushort_t* sKc = sK[cur];
      f32x4 sacc[4][2];
#pragma unroll
      for (int m = 0; m < 4; ++m)
#pragma unroll
        for (int n = 0; n < 2; ++n) sacc[m][n] = zf;
#pragma unroll
      for (int kt = 0; kt < 4; ++kt) {
        bf16x8 kf[4];
#pragma unroll
        for (int m = 0; m < 4; ++m) {
          int row = m * 16 + lq;
          kf[m] = *(const bf16x8*)(sKc + row * 128 + (((kt * 4 + quad) ^ (row & 7)) * 8));
        }
#pragma unroll
        for (int m = 0; m < 4; ++m)
#pragma unroll
          for (int n = 0; n < 2; ++n)
            sacc[m][n] = mfma16(kf[m], qf[n][kt], sacc[m][n]);
      }

      const bool diag = (j >= 2 * T);
#pragma unroll
      for (int n = 0; n < 2; ++n) {
        const int qr = wv * 32 + n * 16 + lq;
        if (diag) {
          const int rowg = T * 128 + qr;
#pragma unroll
          for (int m = 0; m < 4; ++m)
#pragma unroll
            for (int r = 0; r < 4; ++r) {
              int key = j * 64 + m * 16 + quad * 4 + r;
              if (key > rowg) sacc[m][n][r] = -1e30f;
            }
        }
        float rm = -1e30f;
#pragma unroll
        for (int m = 0; m < 4; ++m)
#pragma unroll
          for (int r = 0; r < 4; ++r) rm = fmaxf(rm, sacc[m][n][r]);
        rm = fmaxf(rm, __shfl_xor(rm, 16, 64));
        rm = fmaxf(rm, __shfl_xor(rm, 32, 64));
        float mnew = fmaxf(m_i[n], rm);
        float alpha = __expf(m_i[n] - mnew);
        m_i[n] = mnew;
        float rs = 0.f;
#pragma unroll
        for (int m = 0; m < 4; ++m)
#pragma unroll
          for (int r = 0; r < 4; ++r) {
            float p = __expf(sacc[m][n][r] - mnew);
            sacc[m][n][r] = p;
            rs += p;
          }
        rs += __shfl_xor(rs, 16, 64);
        rs += __shfl_xor(rs, 32, 64);
        l_i[n] = l_i[n] * alpha + rs;
#pragma unroll
        for (int m = 0; m < 8; ++m)
#pragma unroll
          for (int r = 0; r < 4; ++r) oacc[m][n][r] *= alpha;
#pragma unroll
        for (int m = 0; m < 4; ++m) {
          uint32_t lo = (uint32_t)f2bf(sacc[m][n][0]) | ((uint32_t)f2bf(sacc[m][n][1]) << 16);
          uint32_t hi = (uint32_t)f2bf(sacc[m][n][2]) | ((uint32_t)f2bf(sacc[m][n][3]) << 16);
          int gw = m * 2 + (quad >> 1);
          *(uint2*)(sP + qr * 64 + ((gw ^ (qr & 7)) * 8) + (quad & 1) * 4) = make_uint2(lo, hi);
        }
      }

      const ushort_t* sVc = sV[cur];
#pragma unroll
      for (int kt = 0; kt < 2; ++kt) {
        bf16x8 pf[2];
#pragma unroll
        for (int n = 0; n < 2; ++n) {
          int qr = wv * 32 + n * 16 + lq;
          pf[n] = *(const bf16x8*)(sP + qr * 64 + (((kt * 4 + quad) ^ (qr & 7)) * 8));
        }
#pragma unroll
        for (int m = 0; m < 8; ++m) {
          int d = m * 16 + lq;
          bf16x8 vf = *(const bf16x8*)(sVc + d * 64 + (((kt * 4 + quad) ^ (d & 7)) * 8));
#pragma unroll
          for (int n = 0; n < 2; ++n)
            oacc[m][n] = mfma16(vf, pf[n], oacc[m][n]);
        }
      }

      __syncthreads();
    }

    float inv0 = 1.f / l_i[0], inv1 = 1.f / l_i[1];
#pragma unroll
    for (int n = 0; n < 2; ++n) {
      float inv = n ? inv1 : inv0;
      int qr = wv * 32 + n * 16 + lq;
#pragma unroll
      for (int m = 0; m < 8; ++m) {
        uint32_t lo = (uint32_t)f2bf(oacc[m][n][0] * inv) | ((uint32_t)f2bf(oacc[m][n][1] * inv) << 16);
        uint32_t hi = (uint32_t)f2bf(oacc[m][n][2] * inv) | ((uint32_t)f2bf(oacc[m][n][3] * inv) << 16);
        int gw = m * 2 + (quad >> 1);
        *(uint2*)(sO + qr * 128 + ((gw ^ (qr & 7)) * 8) + (quad & 1) * 4) = make_uint2(lo, hi);
      }
    }
    __syncthreads();
#pragma unroll
    for (int it = 0; it < 8; ++it) {
      int qr = it * 16 + (tid >> 4);
      int g = tid & 15;
      uint4 v = *(const uint4*)(sO + qr * 128 + ((g ^ (qr & 7)) * 8));
      *(uint4*)(Ao + ((size_t)(b * SEQ + T * 128 + qr)) * (NHEADS * HDIM) + h * HDIM + g * 8) = v;
    }
  }
}

// ---------------- output projection (fp32 out, XCD-swizzled) ----------------
__global__ __launch_bounds__(256) void out_gemm(const ushort_t* __restrict__ Ain,
                                                const ushort_t* __restrict__ Wo,
                                                float* __restrict__ Y) {
  __shared__ __align__(16) ushort_t As[2][128 * 32];
  __shared__ __align__(16) ushort_t Bs[2][128 * 32];
  const int tid = threadIdx.x;
  const int lin = blockIdx.x;
  const int xcd = lin & 7, s = lin >> 3;
  const int by = xcd + 8 * (s & 1);
  const int bx = s >> 1;
  const int m0 = bx * 128;
  const int n0 = by * 128;

  f32x4 acc[4][4];
  const f32x4 zf = {0.f, 0.f, 0.f, 0.f};
#pragma unroll
  for (int i = 0; i < 4; ++i)
#pragma unroll
    for (int j = 0; j < 4; ++j) acc[i][j] = zf;

  gemm128_core(Ain + (size_t)m0 * HIDDEN, Wo + (size_t)n0 * HIDDEN, &As[0][0], &Bs[0][0], acc, tid);

  const int lane = tid & 63, wv = tid >> 6;
  const int wm = (wv >> 1) * 64, wn = (wv & 1) * 64;
  const int mq = lane & 15, quad = lane >> 4;
#pragma unroll
  for (int i = 0; i < 4; ++i)
#pragma unroll
    for (int j = 0; j < 4; ++j)
#pragma unroll
      for (int r = 0; r < 4; ++r) {
        int m = m0 + wm + i * 16 + quad * 4 + r;
        int o = n0 + wn + j * 16 + mq;
        Y[(size_t)m * HIDDEN + o] = acc[i][j][r];
      }
}

extern "C" void kernel_launch(void* const* d_in, const int* in_sizes, int n_in,
                              void* d_out, int out_size, void* d_ws, size_t ws_size,
                              hipStream_t stream) {
  const float* hs = (const float*)d_in[0];
  const float* Wq = (const float*)d_in[1];
  const float* Wk = (const float*)d_in[2];
  const float* Wv = (const float*)d_in[3];
  const float* Wo = (const float*)d_in[4];
  float* out = (float*)d_out;

  ushort_t* ws  = (ushort_t*)d_ws;
  ushort_t* Xb  = ws;
  ushort_t* Wqb = Xb  + (size_t)MROWS * HIDDEN;
  ushort_t* Wkb = Wqb + (size_t)HIDDEN * HIDDEN;
  ushort_t* Wvb = Wkb + (size_t)HIDDEN * HIDDEN;
  ushort_t* Wob = Wvb + (size_t)HIDDEN * HIDDEN;
  ushort_t* Qb  = Wob + (size_t)HIDDEN * HIDDEN;
  ushort_t* Kb  = Qb  + (size_t)MROWS * HIDDEN;
  ushort_t* Vtb = Kb  + (size_t)MROWS * HIDDEN;
  ushort_t* Ao  = Vtb + (size_t)MROWS * HIDDEN;

  cvt_kernel<<<(MROWS * HIDDEN / 4) / 256, 256, 0, stream>>>(hs, Xb, MROWS * HIDDEN / 4);
  cvt4_kernel<<<dim3((HIDDEN * HIDDEN / 4) / 256, 4), 256, 0, stream>>>(
      Wq, Wk, Wv, Wo, Wqb, Wkb, Wvb, Wob);

  qkv_gemm<<<dim3(MROWS / 128 * 48), 256, 0, stream>>>(Xb, Wqb, Wkb, Wvb, Qb, Kb, Vtb);
  rope_kernel<<<(BATCH * NHEADS * SEQ * 64) / 256, 256, 0, stream>>>(Qb, Kb);
  flash_kernel<<<dim3(256), 256, 0, stream>>>(Qb, Kb, Vtb, Ao);
  out_gemm<<<dim3(512), 256, 0, stream>>>(Ao, Wob, out);
}